// Round 6
// baseline (452.506 us; speedup 1.0000x reference)
//
#include <hip/hip_runtime.h>

#define N_NODES 50000
#define N_EDGES 1000000
#define EMB     64
#define HID     128
#define NLAYER  3
#define NGRAPH  250
#define XFD     7
#define EFD     5
#define BN_EPS  1e-5f

// two-level counting sort geometry
#define BKT_SH 7
#define BKT_SZ 128                              // nodes per bucket
#define NBKT   ((N_NODES + BKT_SZ - 1) / BKT_SZ)  // 391
#define CHKE   4096                             // edges per chunk
#define NCHK   ((N_EDGES + CHKE - 1) / CHKE)    // 245
#define CNTM   (NBKT * NCHK)                    // 95795
#define NB2    ((CNTM + 255) / 256)             // 375  (fits 512-thread scanB)

__device__ __forceinline__ void atomAddF(float* p, float v) {
    __hip_atomic_fetch_add(p, v, __ATOMIC_RELAXED, __HIP_MEMORY_SCOPE_AGENT);
}

// h = x @ xW + xb
__global__ void k_input(const float* __restrict__ x, const float* __restrict__ xW,
                        const float* __restrict__ xb, float* __restrict__ h) {
    int gid = blockIdx.x * 256 + threadIdx.x;
    if (gid >= N_NODES * EMB) return;
    int n = gid >> 6, f = gid & 63;
    float acc = xb[f];
#pragma unroll
    for (int k = 0; k < XFD; ++k) acc = fmaf(x[n * XFD + k], xW[k * EMB + f], acc);
    h[gid] = acc;
}

// ---- phase A: per-chunk coarse-bucket histogram ----
__global__ __launch_bounds__(256) void k_binA(const int* __restrict__ dst,
                                              int* __restrict__ cntmat) {
    __shared__ int hist[NBKT];
    int tid = threadIdx.x, c = blockIdx.x;
    for (int i = tid; i < NBKT; i += 256) hist[i] = 0;
    __syncthreads();
    int e0 = c * CHKE, e1 = min(e0 + CHKE, N_EDGES);
    for (int i = e0 + tid; i < e1; i += 256) atomicAdd(&hist[dst[i] >> BKT_SH], 1);
    __syncthreads();
    for (int b = tid; b < NBKT; b += 256) cntmat[b * NCHK + c] = hist[b];  // bucket-major
}

// ---- 3-phase multi-block exclusive scan ----
__global__ __launch_bounds__(256) void k_gscanA(const int* __restrict__ in, int n,
                                                int* __restrict__ bsum) {
    int tid = threadIdx.x, lane = tid & 63, wid = tid >> 6;
    int i = blockIdx.x * 256 + tid;
    int v = (i < n) ? in[i] : 0;
#pragma unroll
    for (int off = 32; off; off >>= 1) v += __shfl_down(v, off);
    __shared__ int ws[4];
    if (lane == 0) ws[wid] = v;
    __syncthreads();
    if (tid == 0) bsum[blockIdx.x] = ws[0] + ws[1] + ws[2] + ws[3];
}

// 512 threads: handles up to 512 block-sums (NB2=375)
__global__ __launch_bounds__(512) void k_gscanB(const int* __restrict__ bsum, int nb,
                                                int* __restrict__ boff) {
    int tid = threadIdx.x, lane = tid & 63, wid = tid >> 6;
    int v = (tid < nb) ? bsum[tid] : 0;
    int x = v;
#pragma unroll
    for (int off = 1; off < 64; off <<= 1) {
        int y = __shfl_up(x, off);
        if (lane >= off) x += y;
    }
    __shared__ int wtot[8];
    if (lane == 63) wtot[wid] = x;
    __syncthreads();
    int woff = 0;
    for (int w = 0; w < wid; ++w) woff += wtot[w];
    if (tid < nb) boff[tid] = woff + x - v;
}

__global__ __launch_bounds__(256) void k_gscanC(const int* __restrict__ in, int n,
                                                const int* __restrict__ boff,
                                                int* __restrict__ out) {
    int tid = threadIdx.x, lane = tid & 63, wid = tid >> 6;
    int i = blockIdx.x * 256 + tid;
    int v = (i < n) ? in[i] : 0;
    int x = v;
#pragma unroll
    for (int off = 1; off < 64; off <<= 1) {
        int y = __shfl_up(x, off);
        if (lane >= off) x += y;
    }
    __shared__ int wtot[4];
    if (lane == 63) wtot[wid] = x;
    __syncthreads();
    int woff = boff[blockIdx.x];
    for (int w = 0; w < wid; ++w) woff += wtot[w];
    if (i < n) out[i] = woff + x - v;
}

// ---- phase C: coarse scatter, CARRYING ea (R5 lesson: binD's random ea gather
// cost 62MB of line fetches; here ea is read coalesced and written run-local) ----
__global__ __launch_bounds__(256) void k_binC(const int* __restrict__ src,
                                              const int* __restrict__ dst,
                                              const float* __restrict__ ea,
                                              const int* __restrict__ off2,
                                              int2* __restrict__ bufSD,
                                              float4* __restrict__ bufEA,
                                              float* __restrict__ bufE4) {
    __shared__ int cur[NBKT];
    int tid = threadIdx.x, c = blockIdx.x;
    for (int b = tid; b < NBKT; b += 256) cur[b] = off2[b * NCHK + c];
    __syncthreads();
    int e0 = c * CHKE, e1 = min(e0 + CHKE, N_EDGES);
    for (int i = e0 + tid; i < e1; i += 256) {
        int d = dst[i];
        int b = d >> BKT_SH;
        int p = atomicAdd(&cur[b], 1);
        const float* pe = ea + (size_t)i * EFD;
        bufSD[p] = make_int2(src[i], d & (BKT_SZ - 1));
        bufEA[p] = make_float4(pe[0], pe[1], pe[2], pe[3]);
        bufE4[p] = pe[4];
    }
}

// ---- phase D: per-bucket fine sort -> csr + rowstart + aggE (streaming only) ----
__global__ __launch_bounds__(256) void k_binD(const int2* __restrict__ bufSD,
                                              const float4* __restrict__ bufEA,
                                              const float* __restrict__ bufE4,
                                              const int* __restrict__ off2,
                                              int* __restrict__ csr,
                                              int* __restrict__ rowstart,
                                              float* __restrict__ aggE) {
    __shared__ int hist[BKT_SZ];
    __shared__ int cur[BKT_SZ];
    __shared__ float accL[BKT_SZ * EFD];
    __shared__ int wtot[4];
    int tid = threadIdx.x, b = blockIdx.x;
    int bstart = off2[b * NCHK];
    int bend = (b + 1 < NBKT) ? off2[(b + 1) * NCHK] : N_EDGES;
    if (tid < BKT_SZ) hist[tid] = 0;
    for (int i = tid; i < BKT_SZ * EFD; i += 256) accL[i] = 0.f;
    __syncthreads();
    for (int j = bstart + tid; j < bend; j += 256) atomicAdd(&hist[bufSD[j].y], 1);
    __syncthreads();
    int lane = tid & 63, wid = tid >> 6;
    int v = (tid < BKT_SZ) ? hist[tid] : 0, x = v;
#pragma unroll
    for (int off = 1; off < 64; off <<= 1) {
        int y = __shfl_up(x, off);
        if (lane >= off) x += y;
    }
    if (lane == 63) wtot[wid] = x;
    __syncthreads();
    int woff = 0;
    for (int w = 0; w < wid; ++w) woff += wtot[w];
    int ex = woff + x - v;
    if (tid < BKT_SZ) {
        cur[tid] = ex;
        int node = b * BKT_SZ + tid;
        if (node < N_NODES) rowstart[node] = bstart + ex;
    }
    if (b == NBKT - 1 && tid == 0) rowstart[N_NODES] = N_EDGES;
    __syncthreads();
    for (int j = bstart + tid; j < bend; j += 256) {
        int2 t = bufSD[j];
        float4 f4 = bufEA[j];
        float f1 = bufE4[j];
        int p = atomicAdd(&cur[t.y], 1);
        csr[bstart + p] = t.x;
        float* a = accL + t.y * EFD;
        atomicAdd(&a[0], f4.x);
        atomicAdd(&a[1], f4.y);
        atomicAdd(&a[2], f4.z);
        atomicAdd(&a[3], f4.w);
        atomicAdd(&a[4], f1);
    }
    __syncthreads();
    int validN = min(BKT_SZ, N_NODES - b * BKT_SZ);
    for (int i = tid; i < validN * EFD; i += 256)
        aggE[(size_t)b * BKT_SZ * EFD + i] = accL[i];
}

// agg[n] = h[n] + (8*eW[0]+eb) + sum_in h[src] + aggE[n]@eW + deg*eb
__global__ __launch_bounds__(256) void k_agg(const float* __restrict__ h,
                                             float* __restrict__ agg,
                                             const int* __restrict__ rowstart,
                                             const int* __restrict__ csr,
                                             const float* __restrict__ aggE,
                                             const float* __restrict__ eWl,
                                             const float* __restrict__ ebl) {
    int wid = (blockIdx.x * 256 + threadIdx.x) >> 6;
    int lane = threadIdx.x & 63;
    if (wid >= N_NODES) return;
    int n = wid;
    int lg = lane >> 4, lq = lane & 15;
    const float4* h4 = (const float4*)h;
    int j0 = rowstart[n], j1 = rowstart[n + 1];
    float4 acc = make_float4(0.f, 0.f, 0.f, 0.f);
    int j = j0;
    while (j < j1) {
        int take = j1 - j;
        if (take > 64) take = 64;
        int myid = (lane < take) ? csr[j + lane] : 0;
        int nt = (take + 3) >> 2;
        int t = 0;
        for (; t + 4 <= nt; t += 4) {
            int e0 = t * 4 + lg, e1 = e0 + 4, e2 = e0 + 8, e3 = e0 + 12;
            int s0 = __shfl(myid, e0), s1 = __shfl(myid, e1),
                s2 = __shfl(myid, e2), s3 = __shfl(myid, e3);
            float4 v0 = h4[(size_t)s0 * 16 + lq];
            float4 v1 = h4[(size_t)s1 * 16 + lq];
            float4 v2 = h4[(size_t)s2 * 16 + lq];
            float4 v3 = h4[(size_t)s3 * 16 + lq];
            if (e0 < take) { acc.x += v0.x; acc.y += v0.y; acc.z += v0.z; acc.w += v0.w; }
            if (e1 < take) { acc.x += v1.x; acc.y += v1.y; acc.z += v1.z; acc.w += v1.w; }
            if (e2 < take) { acc.x += v2.x; acc.y += v2.y; acc.z += v2.z; acc.w += v2.w; }
            if (e3 < take) { acc.x += v3.x; acc.y += v3.y; acc.z += v3.z; acc.w += v3.w; }
        }
        for (; t < nt; ++t) {
            int e = t * 4 + lg;
            int s = __shfl(myid, e);
            float4 v = h4[(size_t)s * 16 + lq];
            if (e < take) { acc.x += v.x; acc.y += v.y; acc.z += v.z; acc.w += v.w; }
        }
        j += take;
    }
    acc.x += __shfl_xor(acc.x, 16); acc.y += __shfl_xor(acc.y, 16);
    acc.z += __shfl_xor(acc.z, 16); acc.w += __shfl_xor(acc.w, 16);
    acc.x += __shfl_xor(acc.x, 32); acc.y += __shfl_xor(acc.y, 32);
    acc.z += __shfl_xor(acc.z, 32); acc.w += __shfl_xor(acc.w, 32);
    const float4* eW4 = (const float4*)eWl;
    float4 ew0 = eW4[lq], ew1 = eW4[16 + lq], ew2 = eW4[32 + lq],
           ew3 = eW4[48 + lq], ew4 = eW4[64 + lq];
    float4 eb4 = ((const float4*)ebl)[lq];
    float a0 = aggE[n * 5 + 0], a1 = aggE[n * 5 + 1], a2 = aggE[n * 5 + 2],
          a3 = aggE[n * 5 + 3], a4 = aggE[n * 5 + 4];
    float c0 = a0 + 8.f;
    float ce = (float)(j1 - j0) + 1.f;
    float4 bb = h4[(size_t)n * 16 + lq];
    bb.x = fmaf(c0, ew0.x, bb.x); bb.y = fmaf(c0, ew0.y, bb.y);
    bb.z = fmaf(c0, ew0.z, bb.z); bb.w = fmaf(c0, ew0.w, bb.w);
    bb.x = fmaf(a1, ew1.x, bb.x); bb.y = fmaf(a1, ew1.y, bb.y);
    bb.z = fmaf(a1, ew1.z, bb.z); bb.w = fmaf(a1, ew1.w, bb.w);
    bb.x = fmaf(a2, ew2.x, bb.x); bb.y = fmaf(a2, ew2.y, bb.y);
    bb.z = fmaf(a2, ew2.z, bb.z); bb.w = fmaf(a2, ew2.w, bb.w);
    bb.x = fmaf(a3, ew3.x, bb.x); bb.y = fmaf(a3, ew3.y, bb.y);
    bb.z = fmaf(a3, ew3.z, bb.z); bb.w = fmaf(a3, ew3.w, bb.w);
    bb.x = fmaf(a4, ew4.x, bb.x); bb.y = fmaf(a4, ew4.y, bb.y);
    bb.z = fmaf(a4, ew4.z, bb.z); bb.w = fmaf(a4, ew4.w, bb.w);
    bb.x = fmaf(ce, eb4.x, bb.x); bb.y = fmaf(ce, eb4.y, bb.y);
    bb.z = fmaf(ce, eb4.z, bb.z); bb.w = fmaf(ce, eb4.w, bb.w);
    if (lg == 0) {
        ((float4*)agg)[(size_t)n * 16 + lq] =
            make_float4(acc.x + bb.x, acc.y + bb.y, acc.z + bb.z, acc.w + bb.w);
    }
}

// hidden = relu(agg @ W1 + b1)   tile: 32 nodes x 128 hid, 4x4 per thread
__global__ __launch_bounds__(256) void k_mlp1(const float* __restrict__ agg,
                                              float* __restrict__ hidden,
                                              const float* __restrict__ W1l,
                                              const float* __restrict__ b1l) {
    __shared__ float w1s[64 * 128];
    __shared__ float as[32 * 68];
    __shared__ float b1s[128];
    int tid = threadIdx.x;
    int n0 = blockIdx.x * 32;
    const float4* wg = (const float4*)W1l;
    float4* wsh = (float4*)w1s;
#pragma unroll
    for (int i = 0; i < 8; ++i) wsh[tid + i * 256] = wg[tid + i * 256];
    if (tid < 128) b1s[tid] = b1l[tid];
    const float4* ag4 = (const float4*)agg;
#pragma unroll
    for (int i = 0; i < 2; ++i) {
        int idx = tid + i * 256;
        int m = idx >> 4, kq = idx & 15;
        int nn = n0 + m;
        float4 v = make_float4(0.f, 0.f, 0.f, 0.f);
        if (nn < N_NODES) v = ag4[nn * 16 + kq];
        *(float4*)&as[m * 68 + kq * 4] = v;
    }
    __syncthreads();
    int j0 = (tid & 31) * 4;
    int m0 = (tid >> 5) * 4;
    float acc[4][4] = {};
#pragma unroll 8
    for (int k = 0; k < 64; ++k) {
        float4 w = *(const float4*)&w1s[k * 128 + j0];
        float a0 = as[(m0 + 0) * 68 + k];
        float a1 = as[(m0 + 1) * 68 + k];
        float a2 = as[(m0 + 2) * 68 + k];
        float a3 = as[(m0 + 3) * 68 + k];
        acc[0][0] = fmaf(a0, w.x, acc[0][0]); acc[0][1] = fmaf(a0, w.y, acc[0][1]);
        acc[0][2] = fmaf(a0, w.z, acc[0][2]); acc[0][3] = fmaf(a0, w.w, acc[0][3]);
        acc[1][0] = fmaf(a1, w.x, acc[1][0]); acc[1][1] = fmaf(a1, w.y, acc[1][1]);
        acc[1][2] = fmaf(a1, w.z, acc[1][2]); acc[1][3] = fmaf(a1, w.w, acc[1][3]);
        acc[2][0] = fmaf(a2, w.x, acc[2][0]); acc[2][1] = fmaf(a2, w.y, acc[2][1]);
        acc[2][2] = fmaf(a2, w.z, acc[2][2]); acc[2][3] = fmaf(a2, w.w, acc[2][3]);
        acc[3][0] = fmaf(a3, w.x, acc[3][0]); acc[3][1] = fmaf(a3, w.y, acc[3][1]);
        acc[3][2] = fmaf(a3, w.z, acc[3][2]); acc[3][3] = fmaf(a3, w.w, acc[3][3]);
    }
#pragma unroll
    for (int a = 0; a < 4; ++a) {
        int nn = n0 + m0 + a;
        if (nn < N_NODES) {
            float4 o;
            o.x = fmaxf(acc[a][0] + b1s[j0 + 0], 0.f);
            o.y = fmaxf(acc[a][1] + b1s[j0 + 1], 0.f);
            o.z = fmaxf(acc[a][2] + b1s[j0 + 2], 0.f);
            o.w = fmaxf(acc[a][3] + b1s[j0 + 3], 0.f);
            *(float4*)&hidden[nn * HID + j0] = o;
        }
    }
}

// h2 = hidden @ W2 + b2, PLUS fused BN-stats reduction
__global__ __launch_bounds__(256) void k_mlp2(const float* __restrict__ hidden,
                                              float* __restrict__ h2,
                                              const float* __restrict__ W2l,
                                              const float* __restrict__ b2l,
                                              float* __restrict__ stats) {
    __shared__ float w2s[128 * 64];
    __shared__ float hs[64 * 132];
    __shared__ float b2s[64];
    int tid = threadIdx.x;
    int n0 = blockIdx.x * 64;
    const float4* wg = (const float4*)W2l;
    float4* wsh = (float4*)w2s;
#pragma unroll
    for (int i = 0; i < 8; ++i) wsh[tid + i * 256] = wg[tid + i * 256];
    if (tid < 64) b2s[tid] = b2l[tid];
    const float4* hg4 = (const float4*)hidden;
#pragma unroll
    for (int i = 0; i < 8; ++i) {
        int idx = tid + i * 256;
        int m = idx >> 5, kq = idx & 31;
        int nn = n0 + m;
        float4 v = make_float4(0.f, 0.f, 0.f, 0.f);
        if (nn < N_NODES) v = hg4[nn * 32 + kq];
        *(float4*)&hs[m * 132 + kq * 4] = v;
    }
    __syncthreads();
    int f0 = (tid & 15) * 4;
    int m0 = (tid >> 4) * 4;
    float acc[4][4] = {};
#pragma unroll 8
    for (int k = 0; k < 128; ++k) {
        float4 w = *(const float4*)&w2s[k * 64 + f0];
        float a0 = hs[(m0 + 0) * 132 + k];
        float a1 = hs[(m0 + 1) * 132 + k];
        float a2 = hs[(m0 + 2) * 132 + k];
        float a3 = hs[(m0 + 3) * 132 + k];
        acc[0][0] = fmaf(a0, w.x, acc[0][0]); acc[0][1] = fmaf(a0, w.y, acc[0][1]);
        acc[0][2] = fmaf(a0, w.z, acc[0][2]); acc[0][3] = fmaf(a0, w.w, acc[0][3]);
        acc[1][0] = fmaf(a1, w.x, acc[1][0]); acc[1][1] = fmaf(a1, w.y, acc[1][1]);
        acc[1][2] = fmaf(a1, w.z, acc[1][2]); acc[1][3] = fmaf(a1, w.w, acc[1][3]);
        acc[2][0] = fmaf(a2, w.x, acc[2][0]); acc[2][1] = fmaf(a2, w.y, acc[2][1]);
        acc[2][2] = fmaf(a2, w.z, acc[2][2]); acc[2][3] = fmaf(a2, w.w, acc[2][3]);
        acc[3][0] = fmaf(a3, w.x, acc[3][0]); acc[3][1] = fmaf(a3, w.y, acc[3][1]);
        acc[3][2] = fmaf(a3, w.z, acc[3][2]); acc[3][3] = fmaf(a3, w.w, acc[3][3]);
    }
    float sf[4] = {0.f, 0.f, 0.f, 0.f}, qf[4] = {0.f, 0.f, 0.f, 0.f};
#pragma unroll
    for (int a = 0; a < 4; ++a) {
        int nn = n0 + m0 + a;
        if (nn < N_NODES) {
            float v0 = acc[a][0] + b2s[f0 + 0];
            float v1 = acc[a][1] + b2s[f0 + 1];
            float v2 = acc[a][2] + b2s[f0 + 2];
            float v3 = acc[a][3] + b2s[f0 + 3];
            *(float4*)&h2[nn * EMB + f0] = make_float4(v0, v1, v2, v3);
            sf[0] += v0; sf[1] += v1; sf[2] += v2; sf[3] += v3;
            qf[0] = fmaf(v0, v0, qf[0]); qf[1] = fmaf(v1, v1, qf[1]);
            qf[2] = fmaf(v2, v2, qf[2]); qf[3] = fmaf(v3, v3, qf[3]);
        }
    }
    __syncthreads();
    float* red = hs;
    int mg = tid >> 4;
#pragma unroll
    for (int j = 0; j < 4; ++j) {
        red[mg * 64 + f0 + j] = sf[j];
        red[1024 + mg * 64 + f0 + j] = qf[j];
    }
    __syncthreads();
    if (tid < 64) {
        float s = 0.f, q = 0.f;
#pragma unroll
        for (int m = 0; m < 16; ++m) {
            s += red[m * 64 + tid];
            q += red[1024 + m * 64 + tid];
        }
        atomAddF(&stats[tid], s);
        atomAddF(&stats[64 + tid], q);
    }
}

// BN apply + ELU (layers 0,1)
__global__ void k_bn(const float* __restrict__ h2, float* __restrict__ h,
                     const float* __restrict__ stats, const float* __restrict__ gam,
                     const float* __restrict__ bet) {
    int gid = blockIdx.x * 256 + threadIdx.x;
    if (gid >= N_NODES * EMB) return;
    int f = gid & 63;
    const float invN = 1.f / (float)N_NODES;
    float mean = stats[f] * invN;
    float var = stats[64 + f] * invN - mean * mean;
    float inv = rsqrtf(var + BN_EPS);
    float v = (h2[gid] - mean) * inv * gam[f] + bet[f];
    h[gid] = v > 0.f ? v : expm1f(v);
}

// last layer: BN only for the 250 super-nodes, straight to out
__global__ void k_bnout(const float* __restrict__ h2, const int* __restrict__ last,
                        const float* __restrict__ stats, const float* __restrict__ gam,
                        const float* __restrict__ bet, float* __restrict__ out) {
    int gid = blockIdx.x * 256 + threadIdx.x;
    if (gid >= NGRAPH * EMB) return;
    int b = gid >> 6, f = gid & 63;
    const float invN = 1.f / (float)N_NODES;
    float mean = stats[f] * invN;
    float var = stats[64 + f] * invN - mean * mean;
    float inv = rsqrtf(var + BN_EPS);
    out[gid] = (h2[last[b] * EMB + f] - mean) * inv * gam[f] + bet[f];
}

extern "C" void kernel_launch(void* const* d_in, const int* in_sizes, int n_in,
                              void* d_out, int out_size, void* d_ws, size_t ws_size,
                              hipStream_t stream) {
    const float* x   = (const float*)d_in[0];
    const float* ea  = (const float*)d_in[1];
    const int*   eidx= (const int*)d_in[2];
    const int*   last= (const int*)d_in[3];
    const float* xW  = (const float*)d_in[4];
    const float* xb  = (const float*)d_in[5];
    const float* eW  = (const float*)d_in[6];
    const float* eb  = (const float*)d_in[7];
    const float* W1  = (const float*)d_in[8];
    const float* b1  = (const float*)d_in[9];
    const float* W2  = (const float*)d_in[10];
    const float* b2  = (const float*)d_in[11];
    const float* gam = (const float*)d_in[12];
    const float* bet = (const float*)d_in[13];
    float* out = (float*)d_out;

    const int* srcI = eidx;
    const int* dstI = eidx + N_EDGES;

    float* h      = (float*)d_ws;              // N*64  (12.8MB)
    float* agg    = h + N_NODES * EMB;         // N*64  (12.8MB, h2 in loop)
    float* hidden = agg + N_NODES * EMB;       // N*128 (25.6MB)
    float* aggE   = hidden + N_NODES * HID;    // NBKT*BKT_SZ*EFD rounded up
    float* stats  = aggE + NBKT * BKT_SZ * EFD;  // L*128
    int* rowstart = (int*)(stats + NLAYER * 2 * EMB);  // N+1
    int* csr      = rowstart + N_NODES + 1;    // E
    int* cntmat   = csr + N_EDGES;             // CNTM
    int* off2     = cntmat + CNTM;             // CNTM
    int* bsum     = off2 + CNTM;               // NB2
    int* boff     = bsum + NB2;                // NB2
    // sort payload aliases dead-before-loop buffers:
    int2*   bufSD = (int2*)agg;                           // 8MB <= 12.8MB
    float4* bufEA = (float4*)hidden;                      // 16MB
    float*  bufE4 = (float*)(hidden + N_EDGES * 4);       // +4MB = 20MB <= 25.6MB

    hipMemsetAsync(stats, 0, NLAYER * 2 * EMB * sizeof(float), stream);

    k_input<<<(N_NODES * EMB + 255) / 256, 256, 0, stream>>>(x, xW, xb, h);
    k_binA<<<NCHK, 256, 0, stream>>>(dstI, cntmat);
    k_gscanA<<<NB2, 256, 0, stream>>>(cntmat, CNTM, bsum);
    k_gscanB<<<1, 512, 0, stream>>>(bsum, NB2, boff);
    k_gscanC<<<NB2, 256, 0, stream>>>(cntmat, CNTM, boff, off2);
    k_binC<<<NCHK, 256, 0, stream>>>(srcI, dstI, ea, off2, bufSD, bufEA, bufE4);
    k_binD<<<NBKT, 256, 0, stream>>>(bufSD, bufEA, bufE4, off2, csr, rowstart, aggE);

    for (int l = 0; l < NLAYER; ++l) {
        k_agg<<<(N_NODES * 64 + 255) / 256, 256, 0, stream>>>(
            h, agg, rowstart, csr, aggE, eW + l * EFD * EMB, eb + l * EMB);
        k_mlp1<<<(N_NODES + 31) / 32, 256, 0, stream>>>(agg, hidden, W1 + l * EMB * HID,
                                                        b1 + l * HID);
        k_mlp2<<<(N_NODES + 63) / 64, 256, 0, stream>>>(hidden, agg, W2 + l * HID * EMB,
                                                        b2 + l * EMB, stats + l * 2 * EMB);
        if (l < NLAYER - 1) {
            k_bn<<<(N_NODES * EMB + 255) / 256, 256, 0, stream>>>(
                agg, h, stats + l * 2 * EMB, gam + l * EMB, bet + l * EMB);
        } else {
            k_bnout<<<(NGRAPH * EMB + 255) / 256, 256, 0, stream>>>(
                agg, last, stats + l * 2 * EMB, gam + l * EMB, bet + l * EMB, out);
        }
    }
}

// Round 7
// 426.561 us; speedup vs baseline: 1.0608x; 1.0608x over previous
//
#include <hip/hip_runtime.h>

#define N_NODES 50000
#define N_EDGES 1000000
#define EMB     64
#define HID     128
#define NLAYER  3
#define NGRAPH  250
#define XFD     7
#define EFD     5
#define BN_EPS  1e-5f

// two-level counting sort geometry (R6 lesson: 28B payload + fine buckets made
// the coarse scatter the bottleneck. Back to 8B payload, 256-node buckets;
// ea gathered post-sort at full concurrency.)
#define BKT_SH 8
#define BKT_SZ 256                              // nodes per bucket
#define NBKT   ((N_NODES + BKT_SZ - 1) / BKT_SZ)  // 196
#define CHKE   4096
#define NCHK   ((N_EDGES + CHKE - 1) / CHKE)    // 245
#define CNTM   (NBKT * NCHK)                    // 48020
#define NB2    ((CNTM + 255) / 256)             // 188 (<256, fits scanB)

__device__ __forceinline__ void atomAddF(float* p, float v) {
    __hip_atomic_fetch_add(p, v, __ATOMIC_RELAXED, __HIP_MEMORY_SCOPE_AGENT);
}

// h = x @ xW + xb
__global__ void k_input(const float* __restrict__ x, const float* __restrict__ xW,
                        const float* __restrict__ xb, float* __restrict__ h) {
    int gid = blockIdx.x * 256 + threadIdx.x;
    if (gid >= N_NODES * EMB) return;
    int n = gid >> 6, f = gid & 63;
    float acc = xb[f];
#pragma unroll
    for (int k = 0; k < XFD; ++k) acc = fmaf(x[n * XFD + k], xW[k * EMB + f], acc);
    h[gid] = acc;
}

// ---- phase A: per-chunk coarse-bucket histogram ----
__global__ __launch_bounds__(256) void k_binA(const int* __restrict__ dst,
                                              int* __restrict__ cntmat) {
    __shared__ int hist[NBKT];
    int tid = threadIdx.x, c = blockIdx.x;
    for (int i = tid; i < NBKT; i += 256) hist[i] = 0;
    __syncthreads();
    int e0 = c * CHKE, e1 = min(e0 + CHKE, N_EDGES);
    for (int i = e0 + tid; i < e1; i += 256) atomicAdd(&hist[dst[i] >> BKT_SH], 1);
    __syncthreads();
    for (int b = tid; b < NBKT; b += 256) cntmat[b * NCHK + c] = hist[b];  // bucket-major
}

// ---- 3-phase multi-block exclusive scan ----
__global__ __launch_bounds__(256) void k_gscanA(const int* __restrict__ in, int n,
                                                int* __restrict__ bsum) {
    int tid = threadIdx.x, lane = tid & 63, wid = tid >> 6;
    int i = blockIdx.x * 256 + tid;
    int v = (i < n) ? in[i] : 0;
#pragma unroll
    for (int off = 32; off; off >>= 1) v += __shfl_down(v, off);
    __shared__ int ws[4];
    if (lane == 0) ws[wid] = v;
    __syncthreads();
    if (tid == 0) bsum[blockIdx.x] = ws[0] + ws[1] + ws[2] + ws[3];
}

__global__ __launch_bounds__(256) void k_gscanB(const int* __restrict__ bsum, int nb,
                                                int* __restrict__ boff) {
    int tid = threadIdx.x, lane = tid & 63, wid = tid >> 6;
    int v = (tid < nb) ? bsum[tid] : 0;
    int x = v;
#pragma unroll
    for (int off = 1; off < 64; off <<= 1) {
        int y = __shfl_up(x, off);
        if (lane >= off) x += y;
    }
    __shared__ int wtot[4];
    if (lane == 63) wtot[wid] = x;
    __syncthreads();
    int woff = 0;
    for (int w = 0; w < wid; ++w) woff += wtot[w];
    if (tid < nb) boff[tid] = woff + x - v;
}

__global__ __launch_bounds__(256) void k_gscanC(const int* __restrict__ in, int n,
                                                const int* __restrict__ boff,
                                                int* __restrict__ out) {
    int tid = threadIdx.x, lane = tid & 63, wid = tid >> 6;
    int i = blockIdx.x * 256 + tid;
    int v = (i < n) ? in[i] : 0;
    int x = v;
#pragma unroll
    for (int off = 1; off < 64; off <<= 1) {
        int y = __shfl_up(x, off);
        if (lane >= off) x += y;
    }
    __shared__ int wtot[4];
    if (lane == 63) wtot[wid] = x;
    __syncthreads();
    int woff = boff[blockIdx.x];
    for (int w = 0; w < wid; ++w) woff += wtot[w];
    if (i < n) out[i] = woff + x - v;
}

// ---- phase C: coarse scatter of packed {src, d_local<<20|eid} (8B, 21-edge runs) ----
__global__ __launch_bounds__(256) void k_binC(const int* __restrict__ src,
                                              const int* __restrict__ dst,
                                              const int* __restrict__ off2,
                                              int2* __restrict__ bufSD) {
    __shared__ int cur[NBKT];
    int tid = threadIdx.x, c = blockIdx.x;
    for (int b = tid; b < NBKT; b += 256) cur[b] = off2[b * NCHK + c];
    __syncthreads();
    int e0 = c * CHKE, e1 = min(e0 + CHKE, N_EDGES);
    for (int i = e0 + tid; i < e1; i += 256) {
        int d = dst[i];
        int b = d >> BKT_SH;
        int p = atomicAdd(&cur[b], 1);
        bufSD[p] = make_int2(src[i], ((d & (BKT_SZ - 1)) << 20) | i);  // eid<2^20
    }
}

// ---- phase D: per-bucket fine sort -> csr + csrE + rowstart (streaming only) ----
__global__ __launch_bounds__(256) void k_binD(const int2* __restrict__ bufSD,
                                              const int* __restrict__ off2,
                                              int* __restrict__ csr,
                                              int* __restrict__ csrE,
                                              int* __restrict__ rowstart) {
    __shared__ int hist[BKT_SZ];
    __shared__ int cur[BKT_SZ];
    __shared__ int wtot[4];
    int tid = threadIdx.x, b = blockIdx.x;
    int bstart = off2[b * NCHK];
    int bend = (b + 1 < NBKT) ? off2[(b + 1) * NCHK] : N_EDGES;
    hist[tid] = 0;
    __syncthreads();
    for (int j = bstart + tid; j < bend; j += 256)
        atomicAdd(&hist[bufSD[j].y >> 20], 1);
    __syncthreads();
    int lane = tid & 63, wid = tid >> 6;
    int v = hist[tid], x = v;
#pragma unroll
    for (int off = 1; off < 64; off <<= 1) {
        int y = __shfl_up(x, off);
        if (lane >= off) x += y;
    }
    if (lane == 63) wtot[wid] = x;
    __syncthreads();
    int woff = 0;
    for (int w = 0; w < wid; ++w) woff += wtot[w];
    int ex = woff + x - v;
    cur[tid] = ex;
    int node = b * BKT_SZ + tid;
    if (node < N_NODES) rowstart[node] = bstart + ex;
    if (b == NBKT - 1 && tid == 0) rowstart[N_NODES] = N_EDGES;
    __syncthreads();
    for (int j = bstart + tid; j < bend; j += 256) {
        int2 t = bufSD[j];
        int local = t.y >> 20;
        int p = atomicAdd(&cur[local], 1);
        csr[bstart + p] = t.x;
        csrE[bstart + p] = t.y & 0xFFFFF;
    }
}

// aggE[n] = sum of ea over in-edges. Wave per node, 12500 blocks: the random
// ea line-gather (~62MB) runs at full-device concurrency (R5 lesson: same
// gather from 196 blocks was concurrency-starved at 1.7TB/s).
__global__ __launch_bounds__(256) void k_aggE(const int* __restrict__ rowstart,
                                              const int* __restrict__ csrE,
                                              const float* __restrict__ ea,
                                              float* __restrict__ aggE) {
    int wid = (blockIdx.x * 256 + threadIdx.x) >> 6;
    int lane = threadIdx.x & 63;
    if (wid >= N_NODES) return;
    int j0 = rowstart[wid], j1 = rowstart[wid + 1];
    float s0 = 0.f, s1 = 0.f, s2 = 0.f, s3 = 0.f, s4 = 0.f;
    for (int j = j0 + lane; j < j1; j += 64) {
        int e = csrE[j];
        const float* p = ea + (size_t)e * EFD;
        s0 += p[0]; s1 += p[1]; s2 += p[2]; s3 += p[3]; s4 += p[4];
    }
#pragma unroll
    for (int off = 32; off; off >>= 1) {
        s0 += __shfl_down(s0, off);
        s1 += __shfl_down(s1, off);
        s2 += __shfl_down(s2, off);
        s3 += __shfl_down(s3, off);
        s4 += __shfl_down(s4, off);
    }
    if (lane == 0) {
        float* o = aggE + (size_t)wid * EFD;
        o[0] = s0; o[1] = s1; o[2] = s2; o[3] = s3; o[4] = s4;
    }
}

// agg[n] = h[n] + (8*eW[0]+eb) + sum_in h[src] + aggE[n]@eW + deg*eb
__global__ __launch_bounds__(256) void k_agg(const float* __restrict__ h,
                                             float* __restrict__ agg,
                                             const int* __restrict__ rowstart,
                                             const int* __restrict__ csr,
                                             const float* __restrict__ aggE,
                                             const float* __restrict__ eWl,
                                             const float* __restrict__ ebl) {
    int wid = (blockIdx.x * 256 + threadIdx.x) >> 6;
    int lane = threadIdx.x & 63;
    if (wid >= N_NODES) return;
    int n = wid;
    int lg = lane >> 4, lq = lane & 15;
    const float4* h4 = (const float4*)h;
    int j0 = rowstart[n], j1 = rowstart[n + 1];
    float4 acc = make_float4(0.f, 0.f, 0.f, 0.f);
    int j = j0;
    while (j < j1) {
        int take = j1 - j;
        if (take > 64) take = 64;
        int myid = (lane < take) ? csr[j + lane] : 0;
        int nt = (take + 3) >> 2;
        int t = 0;
        for (; t + 4 <= nt; t += 4) {
            int e0 = t * 4 + lg, e1 = e0 + 4, e2 = e0 + 8, e3 = e0 + 12;
            int s0 = __shfl(myid, e0), s1 = __shfl(myid, e1),
                s2 = __shfl(myid, e2), s3 = __shfl(myid, e3);
            float4 v0 = h4[(size_t)s0 * 16 + lq];
            float4 v1 = h4[(size_t)s1 * 16 + lq];
            float4 v2 = h4[(size_t)s2 * 16 + lq];
            float4 v3 = h4[(size_t)s3 * 16 + lq];
            if (e0 < take) { acc.x += v0.x; acc.y += v0.y; acc.z += v0.z; acc.w += v0.w; }
            if (e1 < take) { acc.x += v1.x; acc.y += v1.y; acc.z += v1.z; acc.w += v1.w; }
            if (e2 < take) { acc.x += v2.x; acc.y += v2.y; acc.z += v2.z; acc.w += v2.w; }
            if (e3 < take) { acc.x += v3.x; acc.y += v3.y; acc.z += v3.z; acc.w += v3.w; }
        }
        for (; t < nt; ++t) {
            int e = t * 4 + lg;
            int s = __shfl(myid, e);
            float4 v = h4[(size_t)s * 16 + lq];
            if (e < take) { acc.x += v.x; acc.y += v.y; acc.z += v.z; acc.w += v.w; }
        }
        j += take;
    }
    acc.x += __shfl_xor(acc.x, 16); acc.y += __shfl_xor(acc.y, 16);
    acc.z += __shfl_xor(acc.z, 16); acc.w += __shfl_xor(acc.w, 16);
    acc.x += __shfl_xor(acc.x, 32); acc.y += __shfl_xor(acc.y, 32);
    acc.z += __shfl_xor(acc.z, 32); acc.w += __shfl_xor(acc.w, 32);
    const float4* eW4 = (const float4*)eWl;
    float4 ew0 = eW4[lq], ew1 = eW4[16 + lq], ew2 = eW4[32 + lq],
           ew3 = eW4[48 + lq], ew4 = eW4[64 + lq];
    float4 eb4 = ((const float4*)ebl)[lq];
    float a0 = aggE[n * 5 + 0], a1 = aggE[n * 5 + 1], a2 = aggE[n * 5 + 2],
          a3 = aggE[n * 5 + 3], a4 = aggE[n * 5 + 4];
    float c0 = a0 + 8.f;
    float ce = (float)(j1 - j0) + 1.f;
    float4 bb = h4[(size_t)n * 16 + lq];
    bb.x = fmaf(c0, ew0.x, bb.x); bb.y = fmaf(c0, ew0.y, bb.y);
    bb.z = fmaf(c0, ew0.z, bb.z); bb.w = fmaf(c0, ew0.w, bb.w);
    bb.x = fmaf(a1, ew1.x, bb.x); bb.y = fmaf(a1, ew1.y, bb.y);
    bb.z = fmaf(a1, ew1.z, bb.z); bb.w = fmaf(a1, ew1.w, bb.w);
    bb.x = fmaf(a2, ew2.x, bb.x); bb.y = fmaf(a2, ew2.y, bb.y);
    bb.z = fmaf(a2, ew2.z, bb.z); bb.w = fmaf(a2, ew2.w, bb.w);
    bb.x = fmaf(a3, ew3.x, bb.x); bb.y = fmaf(a3, ew3.y, bb.y);
    bb.z = fmaf(a3, ew3.z, bb.z); bb.w = fmaf(a3, ew3.w, bb.w);
    bb.x = fmaf(a4, ew4.x, bb.x); bb.y = fmaf(a4, ew4.y, bb.y);
    bb.z = fmaf(a4, ew4.z, bb.z); bb.w = fmaf(a4, ew4.w, bb.w);
    bb.x = fmaf(ce, eb4.x, bb.x); bb.y = fmaf(ce, eb4.y, bb.y);
    bb.z = fmaf(ce, eb4.z, bb.z); bb.w = fmaf(ce, eb4.w, bb.w);
    if (lg == 0) {
        ((float4*)agg)[(size_t)n * 16 + lq] =
            make_float4(acc.x + bb.x, acc.y + bb.y, acc.z + bb.z, acc.w + bb.w);
    }
}

// hidden = relu(agg @ W1 + b1)   tile: 32 nodes x 128 hid, 4x4 per thread
__global__ __launch_bounds__(256) void k_mlp1(const float* __restrict__ agg,
                                              float* __restrict__ hidden,
                                              const float* __restrict__ W1l,
                                              const float* __restrict__ b1l) {
    __shared__ float w1s[64 * 128];
    __shared__ float as[32 * 68];
    __shared__ float b1s[128];
    int tid = threadIdx.x;
    int n0 = blockIdx.x * 32;
    const float4* wg = (const float4*)W1l;
    float4* wsh = (float4*)w1s;
#pragma unroll
    for (int i = 0; i < 8; ++i) wsh[tid + i * 256] = wg[tid + i * 256];
    if (tid < 128) b1s[tid] = b1l[tid];
    const float4* ag4 = (const float4*)agg;
#pragma unroll
    for (int i = 0; i < 2; ++i) {
        int idx = tid + i * 256;
        int m = idx >> 4, kq = idx & 15;
        int nn = n0 + m;
        float4 v = make_float4(0.f, 0.f, 0.f, 0.f);
        if (nn < N_NODES) v = ag4[nn * 16 + kq];
        *(float4*)&as[m * 68 + kq * 4] = v;
    }
    __syncthreads();
    int j0 = (tid & 31) * 4;
    int m0 = (tid >> 5) * 4;
    float acc[4][4] = {};
#pragma unroll 8
    for (int k = 0; k < 64; ++k) {
        float4 w = *(const float4*)&w1s[k * 128 + j0];
        float a0 = as[(m0 + 0) * 68 + k];
        float a1 = as[(m0 + 1) * 68 + k];
        float a2 = as[(m0 + 2) * 68 + k];
        float a3 = as[(m0 + 3) * 68 + k];
        acc[0][0] = fmaf(a0, w.x, acc[0][0]); acc[0][1] = fmaf(a0, w.y, acc[0][1]);
        acc[0][2] = fmaf(a0, w.z, acc[0][2]); acc[0][3] = fmaf(a0, w.w, acc[0][3]);
        acc[1][0] = fmaf(a1, w.x, acc[1][0]); acc[1][1] = fmaf(a1, w.y, acc[1][1]);
        acc[1][2] = fmaf(a1, w.z, acc[1][2]); acc[1][3] = fmaf(a1, w.w, acc[1][3]);
        acc[2][0] = fmaf(a2, w.x, acc[2][0]); acc[2][1] = fmaf(a2, w.y, acc[2][1]);
        acc[2][2] = fmaf(a2, w.z, acc[2][2]); acc[2][3] = fmaf(a2, w.w, acc[2][3]);
        acc[3][0] = fmaf(a3, w.x, acc[3][0]); acc[3][1] = fmaf(a3, w.y, acc[3][1]);
        acc[3][2] = fmaf(a3, w.z, acc[3][2]); acc[3][3] = fmaf(a3, w.w, acc[3][3]);
    }
#pragma unroll
    for (int a = 0; a < 4; ++a) {
        int nn = n0 + m0 + a;
        if (nn < N_NODES) {
            float4 o;
            o.x = fmaxf(acc[a][0] + b1s[j0 + 0], 0.f);
            o.y = fmaxf(acc[a][1] + b1s[j0 + 1], 0.f);
            o.z = fmaxf(acc[a][2] + b1s[j0 + 2], 0.f);
            o.w = fmaxf(acc[a][3] + b1s[j0 + 3], 0.f);
            *(float4*)&hidden[nn * HID + j0] = o;
        }
    }
}

// h2 = hidden @ W2 + b2, PLUS fused BN-stats reduction
__global__ __launch_bounds__(256) void k_mlp2(const float* __restrict__ hidden,
                                              float* __restrict__ h2,
                                              const float* __restrict__ W2l,
                                              const float* __restrict__ b2l,
                                              float* __restrict__ stats) {
    __shared__ float w2s[128 * 64];
    __shared__ float hs[64 * 132];
    __shared__ float b2s[64];
    int tid = threadIdx.x;
    int n0 = blockIdx.x * 64;
    const float4* wg = (const float4*)W2l;
    float4* wsh = (float4*)w2s;
#pragma unroll
    for (int i = 0; i < 8; ++i) wsh[tid + i * 256] = wg[tid + i * 256];
    if (tid < 64) b2s[tid] = b2l[tid];
    const float4* hg4 = (const float4*)hidden;
#pragma unroll
    for (int i = 0; i < 8; ++i) {
        int idx = tid + i * 256;
        int m = idx >> 5, kq = idx & 31;
        int nn = n0 + m;
        float4 v = make_float4(0.f, 0.f, 0.f, 0.f);
        if (nn < N_NODES) v = hg4[nn * 32 + kq];
        *(float4*)&hs[m * 132 + kq * 4] = v;
    }
    __syncthreads();
    int f0 = (tid & 15) * 4;
    int m0 = (tid >> 4) * 4;
    float acc[4][4] = {};
#pragma unroll 8
    for (int k = 0; k < 128; ++k) {
        float4 w = *(const float4*)&w2s[k * 64 + f0];
        float a0 = hs[(m0 + 0) * 132 + k];
        float a1 = hs[(m0 + 1) * 132 + k];
        float a2 = hs[(m0 + 2) * 132 + k];
        float a3 = hs[(m0 + 3) * 132 + k];
        acc[0][0] = fmaf(a0, w.x, acc[0][0]); acc[0][1] = fmaf(a0, w.y, acc[0][1]);
        acc[0][2] = fmaf(a0, w.z, acc[0][2]); acc[0][3] = fmaf(a0, w.w, acc[0][3]);
        acc[1][0] = fmaf(a1, w.x, acc[1][0]); acc[1][1] = fmaf(a1, w.y, acc[1][1]);
        acc[1][2] = fmaf(a1, w.z, acc[1][2]); acc[1][3] = fmaf(a1, w.w, acc[1][3]);
        acc[2][0] = fmaf(a2, w.x, acc[2][0]); acc[2][1] = fmaf(a2, w.y, acc[2][1]);
        acc[2][2] = fmaf(a2, w.z, acc[2][2]); acc[2][3] = fmaf(a2, w.w, acc[2][3]);
        acc[3][0] = fmaf(a3, w.x, acc[3][0]); acc[3][1] = fmaf(a3, w.y, acc[3][1]);
        acc[3][2] = fmaf(a3, w.z, acc[3][2]); acc[3][3] = fmaf(a3, w.w, acc[3][3]);
    }
    float sf[4] = {0.f, 0.f, 0.f, 0.f}, qf[4] = {0.f, 0.f, 0.f, 0.f};
#pragma unroll
    for (int a = 0; a < 4; ++a) {
        int nn = n0 + m0 + a;
        if (nn < N_NODES) {
            float v0 = acc[a][0] + b2s[f0 + 0];
            float v1 = acc[a][1] + b2s[f0 + 1];
            float v2 = acc[a][2] + b2s[f0 + 2];
            float v3 = acc[a][3] + b2s[f0 + 3];
            *(float4*)&h2[nn * EMB + f0] = make_float4(v0, v1, v2, v3);
            sf[0] += v0; sf[1] += v1; sf[2] += v2; sf[3] += v3;
            qf[0] = fmaf(v0, v0, qf[0]); qf[1] = fmaf(v1, v1, qf[1]);
            qf[2] = fmaf(v2, v2, qf[2]); qf[3] = fmaf(v3, v3, qf[3]);
        }
    }
    __syncthreads();
    float* red = hs;
    int mg = tid >> 4;
#pragma unroll
    for (int j = 0; j < 4; ++j) {
        red[mg * 64 + f0 + j] = sf[j];
        red[1024 + mg * 64 + f0 + j] = qf[j];
    }
    __syncthreads();
    if (tid < 64) {
        float s = 0.f, q = 0.f;
#pragma unroll
        for (int m = 0; m < 16; ++m) {
            s += red[m * 64 + tid];
            q += red[1024 + m * 64 + tid];
        }
        atomAddF(&stats[tid], s);
        atomAddF(&stats[64 + tid], q);
    }
}

// BN apply + ELU (layers 0,1)
__global__ void k_bn(const float* __restrict__ h2, float* __restrict__ h,
                     const float* __restrict__ stats, const float* __restrict__ gam,
                     const float* __restrict__ bet) {
    int gid = blockIdx.x * 256 + threadIdx.x;
    if (gid >= N_NODES * EMB) return;
    int f = gid & 63;
    const float invN = 1.f / (float)N_NODES;
    float mean = stats[f] * invN;
    float var = stats[64 + f] * invN - mean * mean;
    float inv = rsqrtf(var + BN_EPS);
    float v = (h2[gid] - mean) * inv * gam[f] + bet[f];
    h[gid] = v > 0.f ? v : expm1f(v);
}

// last layer: BN only for the 250 super-nodes, straight to out
__global__ void k_bnout(const float* __restrict__ h2, const int* __restrict__ last,
                        const float* __restrict__ stats, const float* __restrict__ gam,
                        const float* __restrict__ bet, float* __restrict__ out) {
    int gid = blockIdx.x * 256 + threadIdx.x;
    if (gid >= NGRAPH * EMB) return;
    int b = gid >> 6, f = gid & 63;
    const float invN = 1.f / (float)N_NODES;
    float mean = stats[f] * invN;
    float var = stats[64 + f] * invN - mean * mean;
    float inv = rsqrtf(var + BN_EPS);
    out[gid] = (h2[last[b] * EMB + f] - mean) * inv * gam[f] + bet[f];
}

extern "C" void kernel_launch(void* const* d_in, const int* in_sizes, int n_in,
                              void* d_out, int out_size, void* d_ws, size_t ws_size,
                              hipStream_t stream) {
    const float* x   = (const float*)d_in[0];
    const float* ea  = (const float*)d_in[1];
    const int*   eidx= (const int*)d_in[2];
    const int*   last= (const int*)d_in[3];
    const float* xW  = (const float*)d_in[4];
    const float* xb  = (const float*)d_in[5];
    const float* eW  = (const float*)d_in[6];
    const float* eb  = (const float*)d_in[7];
    const float* W1  = (const float*)d_in[8];
    const float* b1  = (const float*)d_in[9];
    const float* W2  = (const float*)d_in[10];
    const float* b2  = (const float*)d_in[11];
    const float* gam = (const float*)d_in[12];
    const float* bet = (const float*)d_in[13];
    float* out = (float*)d_out;

    const int* srcI = eidx;
    const int* dstI = eidx + N_EDGES;

    float* h      = (float*)d_ws;              // N*64  (12.8MB)
    float* agg    = h + N_NODES * EMB;         // N*64  (12.8MB, h2 in loop)
    float* hidden = agg + N_NODES * EMB;       // N*128 (25.6MB)
    float* aggE   = hidden + N_NODES * HID;    // NBKT*BKT_SZ*EFD
    float* stats  = aggE + NBKT * BKT_SZ * EFD;  // L*128
    int* rowstart = (int*)(stats + NLAYER * 2 * EMB);  // N+1
    int* csr      = rowstart + N_NODES + 1;    // E
    int* cntmat   = csr + N_EDGES;             // CNTM
    int* off2     = cntmat + CNTM;             // CNTM
    int* bsum     = off2 + CNTM;               // NB2
    int* boff     = bsum + NB2;                // NB2
    // aliases, dead before the layer loop:
    int2* bufSD   = (int2*)agg;                // 8MB <= 12.8MB
    int*  csrE    = (int*)hidden;              // 4MB <= 25.6MB

    hipMemsetAsync(stats, 0, NLAYER * 2 * EMB * sizeof(float), stream);

    k_input<<<(N_NODES * EMB + 255) / 256, 256, 0, stream>>>(x, xW, xb, h);
    k_binA<<<NCHK, 256, 0, stream>>>(dstI, cntmat);
    k_gscanA<<<NB2, 256, 0, stream>>>(cntmat, CNTM, bsum);
    k_gscanB<<<1, 256, 0, stream>>>(bsum, NB2, boff);
    k_gscanC<<<NB2, 256, 0, stream>>>(cntmat, CNTM, boff, off2);
    k_binC<<<NCHK, 256, 0, stream>>>(srcI, dstI, off2, bufSD);
    k_binD<<<NBKT, 256, 0, stream>>>(bufSD, off2, csr, csrE, rowstart);
    k_aggE<<<(N_NODES * 64 + 255) / 256, 256, 0, stream>>>(rowstart, csrE, ea, aggE);

    for (int l = 0; l < NLAYER; ++l) {
        k_agg<<<(N_NODES * 64 + 255) / 256, 256, 0, stream>>>(
            h, agg, rowstart, csr, aggE, eW + l * EFD * EMB, eb + l * EMB);
        k_mlp1<<<(N_NODES + 31) / 32, 256, 0, stream>>>(agg, hidden, W1 + l * EMB * HID,
                                                        b1 + l * HID);
        k_mlp2<<<(N_NODES + 63) / 64, 256, 0, stream>>>(hidden, agg, W2 + l * HID * EMB,
                                                        b2 + l * EMB, stats + l * 2 * EMB);
        if (l < NLAYER - 1) {
            k_bn<<<(N_NODES * EMB + 255) / 256, 256, 0, stream>>>(
                agg, h, stats + l * 2 * EMB, gam + l * EMB, bet + l * EMB);
        } else {
            k_bnout<<<(NGRAPH * EMB + 255) / 256, 256, 0, stream>>>(
                agg, last, stats + l * 2 * EMB, gam + l * EMB, bet + l * EMB, out);
        }
    }
}

// Round 8
// 409.263 us; speedup vs baseline: 1.1057x; 1.0423x over previous
//
#include <hip/hip_runtime.h>

#define N_NODES 50000
#define N_EDGES 1000000
#define EMB     64
#define HID     128
#define NLAYER  3
#define NGRAPH  250
#define XFD     7
#define EFD     5
#define BN_EPS  1e-5f

// two-level counting sort geometry
#define BKT_SH 8
#define BKT_SZ 256
#define NBKT   ((N_NODES + BKT_SZ - 1) / BKT_SZ)  // 196
#define CHKE   4096
#define NCHK   ((N_EDGES + CHKE - 1) / CHKE)      // 245
#define CNTM   (NBKT * NCHK)                      // 48020
#define NB2    ((CNTM + 255) / 256)               // 188

__device__ __forceinline__ void atomAddF(float* p, float v) {
    __hip_atomic_fetch_add(p, v, __ATOMIC_RELAXED, __HIP_MEMORY_SCOPE_AGENT);
}

// bf16 helpers (0.1 output threshold gives ample headroom; fp32 accumulate kept)
__device__ __forceinline__ unsigned short f2bf(float f) {
    unsigned int u = __float_as_uint(f);
    u += 0x7fffu + ((u >> 16) & 1u);  // round-to-nearest-even
    return (unsigned short)(u >> 16);
}
__device__ __forceinline__ float bf2f(unsigned short s) {
    return __uint_as_float(((unsigned int)s) << 16);
}
__device__ __forceinline__ float4 bf4(ushort4 u) {
    return make_float4(bf2f(u.x), bf2f(u.y), bf2f(u.z), bf2f(u.w));
}

// h(bf16) = x @ xW + xb
__global__ void k_input(const float* __restrict__ x, const float* __restrict__ xW,
                        const float* __restrict__ xb, unsigned short* __restrict__ h) {
    int gid = blockIdx.x * 256 + threadIdx.x;
    if (gid >= N_NODES * EMB) return;
    int n = gid >> 6, f = gid & 63;
    float acc = xb[f];
#pragma unroll
    for (int k = 0; k < XFD; ++k) acc = fmaf(x[n * XFD + k], xW[k * EMB + f], acc);
    h[gid] = f2bf(acc);
}

// ---- phase A: per-chunk coarse-bucket histogram ----
__global__ __launch_bounds__(256) void k_binA(const int* __restrict__ dst,
                                              int* __restrict__ cntmat) {
    __shared__ int hist[NBKT];
    int tid = threadIdx.x, c = blockIdx.x;
    for (int i = tid; i < NBKT; i += 256) hist[i] = 0;
    __syncthreads();
    int e0 = c * CHKE, e1 = min(e0 + CHKE, N_EDGES);
    for (int i = e0 + tid; i < e1; i += 256) atomicAdd(&hist[dst[i] >> BKT_SH], 1);
    __syncthreads();
    for (int b = tid; b < NBKT; b += 256) cntmat[b * NCHK + c] = hist[b];
}

// ---- 3-phase multi-block exclusive scan ----
__global__ __launch_bounds__(256) void k_gscanA(const int* __restrict__ in, int n,
                                                int* __restrict__ bsum) {
    int tid = threadIdx.x, lane = tid & 63, wid = tid >> 6;
    int i = blockIdx.x * 256 + tid;
    int v = (i < n) ? in[i] : 0;
#pragma unroll
    for (int off = 32; off; off >>= 1) v += __shfl_down(v, off);
    __shared__ int ws[4];
    if (lane == 0) ws[wid] = v;
    __syncthreads();
    if (tid == 0) bsum[blockIdx.x] = ws[0] + ws[1] + ws[2] + ws[3];
}

__global__ __launch_bounds__(256) void k_gscanB(const int* __restrict__ bsum, int nb,
                                                int* __restrict__ boff) {
    int tid = threadIdx.x, lane = tid & 63, wid = tid >> 6;
    int v = (tid < nb) ? bsum[tid] : 0;
    int x = v;
#pragma unroll
    for (int off = 1; off < 64; off <<= 1) {
        int y = __shfl_up(x, off);
        if (lane >= off) x += y;
    }
    __shared__ int wtot[4];
    if (lane == 63) wtot[wid] = x;
    __syncthreads();
    int woff = 0;
    for (int w = 0; w < wid; ++w) woff += wtot[w];
    if (tid < nb) boff[tid] = woff + x - v;
}

__global__ __launch_bounds__(256) void k_gscanC(const int* __restrict__ in, int n,
                                                const int* __restrict__ boff,
                                                int* __restrict__ out) {
    int tid = threadIdx.x, lane = tid & 63, wid = tid >> 6;
    int i = blockIdx.x * 256 + tid;
    int v = (i < n) ? in[i] : 0;
    int x = v;
#pragma unroll
    for (int off = 1; off < 64; off <<= 1) {
        int y = __shfl_up(x, off);
        if (lane >= off) x += y;
    }
    __shared__ int wtot[4];
    if (lane == 63) wtot[wid] = x;
    __syncthreads();
    int woff = boff[blockIdx.x];
    for (int w = 0; w < wid; ++w) woff += wtot[w];
    if (i < n) out[i] = woff + x - v;
}

// ---- phase C: coarse scatter of packed {src, d_local<<20|eid} ----
__global__ __launch_bounds__(256) void k_binC(const int* __restrict__ src,
                                              const int* __restrict__ dst,
                                              const int* __restrict__ off2,
                                              int2* __restrict__ bufSD) {
    __shared__ int cur[NBKT];
    int tid = threadIdx.x, c = blockIdx.x;
    for (int b = tid; b < NBKT; b += 256) cur[b] = off2[b * NCHK + c];
    __syncthreads();
    int e0 = c * CHKE, e1 = min(e0 + CHKE, N_EDGES);
    for (int i = e0 + tid; i < e1; i += 256) {
        int d = dst[i];
        int b = d >> BKT_SH;
        int p = atomicAdd(&cur[b], 1);
        bufSD[p] = make_int2(src[i], ((d & (BKT_SZ - 1)) << 20) | i);
    }
}

// ---- phase D: per-bucket fine sort -> csr + csrE + rowstart ----
__global__ __launch_bounds__(256) void k_binD(const int2* __restrict__ bufSD,
                                              const int* __restrict__ off2,
                                              int* __restrict__ csr,
                                              int* __restrict__ csrE,
                                              int* __restrict__ rowstart) {
    __shared__ int hist[BKT_SZ];
    __shared__ int cur[BKT_SZ];
    __shared__ int wtot[4];
    int tid = threadIdx.x, b = blockIdx.x;
    int bstart = off2[b * NCHK];
    int bend = (b + 1 < NBKT) ? off2[(b + 1) * NCHK] : N_EDGES;
    hist[tid] = 0;
    __syncthreads();
    for (int j = bstart + tid; j < bend; j += 256)
        atomicAdd(&hist[bufSD[j].y >> 20], 1);
    __syncthreads();
    int lane = tid & 63, wid = tid >> 6;
    int v = hist[tid], x = v;
#pragma unroll
    for (int off = 1; off < 64; off <<= 1) {
        int y = __shfl_up(x, off);
        if (lane >= off) x += y;
    }
    if (lane == 63) wtot[wid] = x;
    __syncthreads();
    int woff = 0;
    for (int w = 0; w < wid; ++w) woff += wtot[w];
    int ex = woff + x - v;
    cur[tid] = ex;
    int node = b * BKT_SZ + tid;
    if (node < N_NODES) rowstart[node] = bstart + ex;
    if (b == NBKT - 1 && tid == 0) rowstart[N_NODES] = N_EDGES;
    __syncthreads();
    for (int j = bstart + tid; j < bend; j += 256) {
        int2 t = bufSD[j];
        int local = t.y >> 20;
        int p = atomicAdd(&cur[local], 1);
        csr[bstart + p] = t.x;
        csrE[bstart + p] = t.y & 0xFFFFF;
    }
}

// aggE[n] = sum of ea over in-edges (wave/node, full-device concurrency)
__global__ __launch_bounds__(256) void k_aggE(const int* __restrict__ rowstart,
                                              const int* __restrict__ csrE,
                                              const float* __restrict__ ea,
                                              float* __restrict__ aggE) {
    int wid = (blockIdx.x * 256 + threadIdx.x) >> 6;
    int lane = threadIdx.x & 63;
    if (wid >= N_NODES) return;
    int j0 = rowstart[wid], j1 = rowstart[wid + 1];
    float s0 = 0.f, s1 = 0.f, s2 = 0.f, s3 = 0.f, s4 = 0.f;
    for (int j = j0 + lane; j < j1; j += 64) {
        int e = csrE[j];
        const float* p = ea + (size_t)e * EFD;
        s0 += p[0]; s1 += p[1]; s2 += p[2]; s3 += p[3]; s4 += p[4];
    }
#pragma unroll
    for (int off = 32; off; off >>= 1) {
        s0 += __shfl_down(s0, off);
        s1 += __shfl_down(s1, off);
        s2 += __shfl_down(s2, off);
        s3 += __shfl_down(s3, off);
        s4 += __shfl_down(s4, off);
    }
    if (lane == 0) {
        float* o = aggE + (size_t)wid * EFD;
        o[0] = s0; o[1] = s1; o[2] = s2; o[3] = s3; o[4] = s4;
    }
}

// agg(f32) = h[n] + (8*eW[0]+eb) + sum_in h[src] + aggE[n]@eW + deg*eb
// h is bf16: row = 128B = 16 lanes x ushort4; fp32 accumulate.
__global__ __launch_bounds__(256) void k_agg(const unsigned short* __restrict__ h,
                                             float* __restrict__ agg,
                                             const int* __restrict__ rowstart,
                                             const int* __restrict__ csr,
                                             const float* __restrict__ aggE,
                                             const float* __restrict__ eWl,
                                             const float* __restrict__ ebl) {
    int wid = (blockIdx.x * 256 + threadIdx.x) >> 6;
    int lane = threadIdx.x & 63;
    if (wid >= N_NODES) return;
    int n = wid;
    int lg = lane >> 4, lq = lane & 15;
    const ushort4* hb = (const ushort4*)h;
    int j0 = rowstart[n], j1 = rowstart[n + 1];
    float4 acc = make_float4(0.f, 0.f, 0.f, 0.f);
    int j = j0;
    while (j < j1) {
        int take = j1 - j;
        if (take > 64) take = 64;
        int myid = (lane < take) ? csr[j + lane] : 0;
        int nt = (take + 3) >> 2;
        int t = 0;
        for (; t + 4 <= nt; t += 4) {
            int e0 = t * 4 + lg, e1 = e0 + 4, e2 = e0 + 8, e3 = e0 + 12;
            int s0 = __shfl(myid, e0), s1 = __shfl(myid, e1),
                s2 = __shfl(myid, e2), s3 = __shfl(myid, e3);
            ushort4 u0 = hb[(size_t)s0 * 16 + lq];
            ushort4 u1 = hb[(size_t)s1 * 16 + lq];
            ushort4 u2 = hb[(size_t)s2 * 16 + lq];
            ushort4 u3 = hb[(size_t)s3 * 16 + lq];
            float4 v0 = bf4(u0), v1 = bf4(u1), v2 = bf4(u2), v3 = bf4(u3);
            if (e0 < take) { acc.x += v0.x; acc.y += v0.y; acc.z += v0.z; acc.w += v0.w; }
            if (e1 < take) { acc.x += v1.x; acc.y += v1.y; acc.z += v1.z; acc.w += v1.w; }
            if (e2 < take) { acc.x += v2.x; acc.y += v2.y; acc.z += v2.z; acc.w += v2.w; }
            if (e3 < take) { acc.x += v3.x; acc.y += v3.y; acc.z += v3.z; acc.w += v3.w; }
        }
        for (; t < nt; ++t) {
            int e = t * 4 + lg;
            int s = __shfl(myid, e);
            float4 v = bf4(hb[(size_t)s * 16 + lq]);
            if (e < take) { acc.x += v.x; acc.y += v.y; acc.z += v.z; acc.w += v.w; }
        }
        j += take;
    }
    acc.x += __shfl_xor(acc.x, 16); acc.y += __shfl_xor(acc.y, 16);
    acc.z += __shfl_xor(acc.z, 16); acc.w += __shfl_xor(acc.w, 16);
    acc.x += __shfl_xor(acc.x, 32); acc.y += __shfl_xor(acc.y, 32);
    acc.z += __shfl_xor(acc.z, 32); acc.w += __shfl_xor(acc.w, 32);
    const float4* eW4 = (const float4*)eWl;
    float4 ew0 = eW4[lq], ew1 = eW4[16 + lq], ew2 = eW4[32 + lq],
           ew3 = eW4[48 + lq], ew4 = eW4[64 + lq];
    float4 eb4 = ((const float4*)ebl)[lq];
    float a0 = aggE[n * 5 + 0], a1 = aggE[n * 5 + 1], a2 = aggE[n * 5 + 2],
          a3 = aggE[n * 5 + 3], a4 = aggE[n * 5 + 4];
    float c0 = a0 + 8.f;
    float ce = (float)(j1 - j0) + 1.f;
    float4 bb = bf4(hb[(size_t)n * 16 + lq]);  // self term
    bb.x = fmaf(c0, ew0.x, bb.x); bb.y = fmaf(c0, ew0.y, bb.y);
    bb.z = fmaf(c0, ew0.z, bb.z); bb.w = fmaf(c0, ew0.w, bb.w);
    bb.x = fmaf(a1, ew1.x, bb.x); bb.y = fmaf(a1, ew1.y, bb.y);
    bb.z = fmaf(a1, ew1.z, bb.z); bb.w = fmaf(a1, ew1.w, bb.w);
    bb.x = fmaf(a2, ew2.x, bb.x); bb.y = fmaf(a2, ew2.y, bb.y);
    bb.z = fmaf(a2, ew2.z, bb.z); bb.w = fmaf(a2, ew2.w, bb.w);
    bb.x = fmaf(a3, ew3.x, bb.x); bb.y = fmaf(a3, ew3.y, bb.y);
    bb.z = fmaf(a3, ew3.z, bb.z); bb.w = fmaf(a3, ew3.w, bb.w);
    bb.x = fmaf(a4, ew4.x, bb.x); bb.y = fmaf(a4, ew4.y, bb.y);
    bb.z = fmaf(a4, ew4.z, bb.z); bb.w = fmaf(a4, ew4.w, bb.w);
    bb.x = fmaf(ce, eb4.x, bb.x); bb.y = fmaf(ce, eb4.y, bb.y);
    bb.z = fmaf(ce, eb4.z, bb.z); bb.w = fmaf(ce, eb4.w, bb.w);
    if (lg == 0) {
        ((float4*)agg)[(size_t)n * 16 + lq] =
            make_float4(acc.x + bb.x, acc.y + bb.y, acc.z + bb.z, acc.w + bb.w);
    }
}

// hidden(bf16) = relu(agg @ W1 + b1)   tile: 32 nodes x 128 hid
__global__ __launch_bounds__(256) void k_mlp1(const float* __restrict__ agg,
                                              unsigned short* __restrict__ hidden,
                                              const float* __restrict__ W1l,
                                              const float* __restrict__ b1l) {
    __shared__ float w1s[64 * 128];
    __shared__ float as[32 * 68];
    __shared__ float b1s[128];
    int tid = threadIdx.x;
    int n0 = blockIdx.x * 32;
    const float4* wg = (const float4*)W1l;
    float4* wsh = (float4*)w1s;
#pragma unroll
    for (int i = 0; i < 8; ++i) wsh[tid + i * 256] = wg[tid + i * 256];
    if (tid < 128) b1s[tid] = b1l[tid];
    const float4* ag4 = (const float4*)agg;
#pragma unroll
    for (int i = 0; i < 2; ++i) {
        int idx = tid + i * 256;
        int m = idx >> 4, kq = idx & 15;
        int nn = n0 + m;
        float4 v = make_float4(0.f, 0.f, 0.f, 0.f);
        if (nn < N_NODES) v = ag4[nn * 16 + kq];
        *(float4*)&as[m * 68 + kq * 4] = v;
    }
    __syncthreads();
    int j0 = (tid & 31) * 4;
    int m0 = (tid >> 5) * 4;
    float acc[4][4] = {};
#pragma unroll 8
    for (int k = 0; k < 64; ++k) {
        float4 w = *(const float4*)&w1s[k * 128 + j0];
        float a0 = as[(m0 + 0) * 68 + k];
        float a1 = as[(m0 + 1) * 68 + k];
        float a2 = as[(m0 + 2) * 68 + k];
        float a3 = as[(m0 + 3) * 68 + k];
        acc[0][0] = fmaf(a0, w.x, acc[0][0]); acc[0][1] = fmaf(a0, w.y, acc[0][1]);
        acc[0][2] = fmaf(a0, w.z, acc[0][2]); acc[0][3] = fmaf(a0, w.w, acc[0][3]);
        acc[1][0] = fmaf(a1, w.x, acc[1][0]); acc[1][1] = fmaf(a1, w.y, acc[1][1]);
        acc[1][2] = fmaf(a1, w.z, acc[1][2]); acc[1][3] = fmaf(a1, w.w, acc[1][3]);
        acc[2][0] = fmaf(a2, w.x, acc[2][0]); acc[2][1] = fmaf(a2, w.y, acc[2][1]);
        acc[2][2] = fmaf(a2, w.z, acc[2][2]); acc[2][3] = fmaf(a2, w.w, acc[2][3]);
        acc[3][0] = fmaf(a3, w.x, acc[3][0]); acc[3][1] = fmaf(a3, w.y, acc[3][1]);
        acc[3][2] = fmaf(a3, w.z, acc[3][2]); acc[3][3] = fmaf(a3, w.w, acc[3][3]);
    }
    ushort4* hid4 = (ushort4*)hidden;
#pragma unroll
    for (int a = 0; a < 4; ++a) {
        int nn = n0 + m0 + a;
        if (nn < N_NODES) {
            ushort4 o;
            o.x = f2bf(fmaxf(acc[a][0] + b1s[j0 + 0], 0.f));
            o.y = f2bf(fmaxf(acc[a][1] + b1s[j0 + 1], 0.f));
            o.z = f2bf(fmaxf(acc[a][2] + b1s[j0 + 2], 0.f));
            o.w = f2bf(fmaxf(acc[a][3] + b1s[j0 + 3], 0.f));
            hid4[(size_t)nn * 32 + (j0 >> 2)] = o;
        }
    }
}

// h2(f32) = hidden(bf16) @ W2 + b2, PLUS fused BN-stats reduction
__global__ __launch_bounds__(256) void k_mlp2(const unsigned short* __restrict__ hidden,
                                              float* __restrict__ h2,
                                              const float* __restrict__ W2l,
                                              const float* __restrict__ b2l,
                                              float* __restrict__ stats) {
    __shared__ float w2s[128 * 64];
    __shared__ float hs[64 * 132];
    __shared__ float b2s[64];
    int tid = threadIdx.x;
    int n0 = blockIdx.x * 64;
    const float4* wg = (const float4*)W2l;
    float4* wsh = (float4*)w2s;
#pragma unroll
    for (int i = 0; i < 8; ++i) wsh[tid + i * 256] = wg[tid + i * 256];
    if (tid < 64) b2s[tid] = b2l[tid];
    const ushort4* hb4 = (const ushort4*)hidden;
#pragma unroll
    for (int i = 0; i < 8; ++i) {
        int idx = tid + i * 256;
        int m = idx >> 5, kq = idx & 31;
        int nn = n0 + m;
        float4 v = make_float4(0.f, 0.f, 0.f, 0.f);
        if (nn < N_NODES) v = bf4(hb4[(size_t)nn * 32 + kq]);
        *(float4*)&hs[m * 132 + kq * 4] = v;
    }
    __syncthreads();
    int f0 = (tid & 15) * 4;
    int m0 = (tid >> 4) * 4;
    float acc[4][4] = {};
#pragma unroll 8
    for (int k = 0; k < 128; ++k) {
        float4 w = *(const float4*)&w2s[k * 64 + f0];
        float a0 = hs[(m0 + 0) * 132 + k];
        float a1 = hs[(m0 + 1) * 132 + k];
        float a2 = hs[(m0 + 2) * 132 + k];
        float a3 = hs[(m0 + 3) * 132 + k];
        acc[0][0] = fmaf(a0, w.x, acc[0][0]); acc[0][1] = fmaf(a0, w.y, acc[0][1]);
        acc[0][2] = fmaf(a0, w.z, acc[0][2]); acc[0][3] = fmaf(a0, w.w, acc[0][3]);
        acc[1][0] = fmaf(a1, w.x, acc[1][0]); acc[1][1] = fmaf(a1, w.y, acc[1][1]);
        acc[1][2] = fmaf(a1, w.z, acc[1][2]); acc[1][3] = fmaf(a1, w.w, acc[1][3]);
        acc[2][0] = fmaf(a2, w.x, acc[2][0]); acc[2][1] = fmaf(a2, w.y, acc[2][1]);
        acc[2][2] = fmaf(a2, w.z, acc[2][2]); acc[2][3] = fmaf(a2, w.w, acc[2][3]);
        acc[3][0] = fmaf(a3, w.x, acc[3][0]); acc[3][1] = fmaf(a3, w.y, acc[3][1]);
        acc[3][2] = fmaf(a3, w.z, acc[3][2]); acc[3][3] = fmaf(a3, w.w, acc[3][3]);
    }
    float sf[4] = {0.f, 0.f, 0.f, 0.f}, qf[4] = {0.f, 0.f, 0.f, 0.f};
#pragma unroll
    for (int a = 0; a < 4; ++a) {
        int nn = n0 + m0 + a;
        if (nn < N_NODES) {
            float v0 = acc[a][0] + b2s[f0 + 0];
            float v1 = acc[a][1] + b2s[f0 + 1];
            float v2 = acc[a][2] + b2s[f0 + 2];
            float v3 = acc[a][3] + b2s[f0 + 3];
            *(float4*)&h2[nn * EMB + f0] = make_float4(v0, v1, v2, v3);
            sf[0] += v0; sf[1] += v1; sf[2] += v2; sf[3] += v3;
            qf[0] = fmaf(v0, v0, qf[0]); qf[1] = fmaf(v1, v1, qf[1]);
            qf[2] = fmaf(v2, v2, qf[2]); qf[3] = fmaf(v3, v3, qf[3]);
        }
    }
    __syncthreads();
    float* red = hs;
    int mg = tid >> 4;
#pragma unroll
    for (int j = 0; j < 4; ++j) {
        red[mg * 64 + f0 + j] = sf[j];
        red[1024 + mg * 64 + f0 + j] = qf[j];
    }
    __syncthreads();
    if (tid < 64) {
        float s = 0.f, q = 0.f;
#pragma unroll
        for (int m = 0; m < 16; ++m) {
            s += red[m * 64 + tid];
            q += red[1024 + m * 64 + tid];
        }
        atomAddF(&stats[tid], s);
        atomAddF(&stats[64 + tid], q);
    }
}

// BN apply + ELU (layers 0,1): h(bf16) = elu(bn(h2))
__global__ void k_bn(const float* __restrict__ h2, unsigned short* __restrict__ h,
                     const float* __restrict__ stats, const float* __restrict__ gam,
                     const float* __restrict__ bet) {
    int gid = blockIdx.x * 256 + threadIdx.x;
    if (gid >= N_NODES * EMB) return;
    int f = gid & 63;
    const float invN = 1.f / (float)N_NODES;
    float mean = stats[f] * invN;
    float var = stats[64 + f] * invN - mean * mean;
    float inv = rsqrtf(var + BN_EPS);
    float v = (h2[gid] - mean) * inv * gam[f] + bet[f];
    h[gid] = f2bf(v > 0.f ? v : expm1f(v));
}

// last layer: BN only for the 250 super-nodes (h2 stays fp32)
__global__ void k_bnout(const float* __restrict__ h2, const int* __restrict__ last,
                        const float* __restrict__ stats, const float* __restrict__ gam,
                        const float* __restrict__ bet, float* __restrict__ out) {
    int gid = blockIdx.x * 256 + threadIdx.x;
    if (gid >= NGRAPH * EMB) return;
    int b = gid >> 6, f = gid & 63;
    const float invN = 1.f / (float)N_NODES;
    float mean = stats[f] * invN;
    float var = stats[64 + f] * invN - mean * mean;
    float inv = rsqrtf(var + BN_EPS);
    out[gid] = (h2[last[b] * EMB + f] - mean) * inv * gam[f] + bet[f];
}

extern "C" void kernel_launch(void* const* d_in, const int* in_sizes, int n_in,
                              void* d_out, int out_size, void* d_ws, size_t ws_size,
                              hipStream_t stream) {
    const float* x   = (const float*)d_in[0];
    const float* ea  = (const float*)d_in[1];
    const int*   eidx= (const int*)d_in[2];
    const int*   last= (const int*)d_in[3];
    const float* xW  = (const float*)d_in[4];
    const float* xb  = (const float*)d_in[5];
    const float* eW  = (const float*)d_in[6];
    const float* eb  = (const float*)d_in[7];
    const float* W1  = (const float*)d_in[8];
    const float* b1  = (const float*)d_in[9];
    const float* W2  = (const float*)d_in[10];
    const float* b2  = (const float*)d_in[11];
    const float* gam = (const float*)d_in[12];
    const float* bet = (const float*)d_in[13];
    float* out = (float*)d_out;

    const int* srcI = eidx;
    const int* dstI = eidx + N_EDGES;

    // slots kept float-sized from R7 layout; bf16 arrays use half the slot
    float* hslot  = (float*)d_ws;              // N*64 floats (h bf16 uses half)
    float* agg    = hslot + N_NODES * EMB;     // N*64 f32 (h2 in loop)
    float* hidslot= agg + N_NODES * EMB;       // N*128 floats (hidden bf16 uses half)
    float* aggE   = hidslot + N_NODES * HID;   // NBKT*BKT_SZ*EFD
    float* stats  = aggE + NBKT * BKT_SZ * EFD;  // L*128
    int* rowstart = (int*)(stats + NLAYER * 2 * EMB);  // N+1
    int* csr      = rowstart + N_NODES + 1;    // E
    int* cntmat   = csr + N_EDGES;             // CNTM
    int* off2     = cntmat + CNTM;             // CNTM
    int* bsum     = off2 + CNTM;               // NB2
    int* boff     = bsum + NB2;                // NB2
    unsigned short* h      = (unsigned short*)hslot;
    unsigned short* hidden = (unsigned short*)hidslot;
    // aliases, dead before the layer loop:
    int2* bufSD   = (int2*)agg;                // 8MB <= 12.8MB
    int*  csrE    = (int*)hidslot;             // 4MB (dead once aggE built)

    hipMemsetAsync(stats, 0, NLAYER * 2 * EMB * sizeof(float), stream);

    k_input<<<(N_NODES * EMB + 255) / 256, 256, 0, stream>>>(x, xW, xb, h);
    k_binA<<<NCHK, 256, 0, stream>>>(dstI, cntmat);
    k_gscanA<<<NB2, 256, 0, stream>>>(cntmat, CNTM, bsum);
    k_gscanB<<<1, 256, 0, stream>>>(bsum, NB2, boff);
    k_gscanC<<<NB2, 256, 0, stream>>>(cntmat, CNTM, boff, off2);
    k_binC<<<NCHK, 256, 0, stream>>>(srcI, dstI, off2, bufSD);
    k_binD<<<NBKT, 256, 0, stream>>>(bufSD, off2, csr, csrE, rowstart);
    k_aggE<<<(N_NODES * 64 + 255) / 256, 256, 0, stream>>>(rowstart, csrE, ea, aggE);

    for (int l = 0; l < NLAYER; ++l) {
        k_agg<<<(N_NODES * 64 + 255) / 256, 256, 0, stream>>>(
            h, agg, rowstart, csr, aggE, eW + l * EFD * EMB, eb + l * EMB);
        k_mlp1<<<(N_NODES + 31) / 32, 256, 0, stream>>>(agg, hidden, W1 + l * EMB * HID,
                                                        b1 + l * HID);
        k_mlp2<<<(N_NODES + 63) / 64, 256, 0, stream>>>(hidden, agg, W2 + l * HID * EMB,
                                                        b2 + l * EMB, stats + l * 2 * EMB);
        if (l < NLAYER - 1) {
            k_bn<<<(N_NODES * EMB + 255) / 256, 256, 0, stream>>>(
                agg, h, stats + l * 2 * EMB, gam + l * EMB, bet + l * EMB);
        } else {
            k_bnout<<<(NGRAPH * EMB + 255) / 256, 256, 0, stream>>>(
                agg, last, stats + l * 2 * EMB, gam + l * EMB, bet + l * EMB, out);
        }
    }
}

// Round 9
// 400.445 us; speedup vs baseline: 1.1300x; 1.0220x over previous
//
#include <hip/hip_runtime.h>

#define N_NODES 50000
#define N_EDGES 1000000
#define EMB     64
#define HID     128
#define NLAYER  3
#define NGRAPH  250
#define XFD     7
#define EFD     5
#define BN_EPS  1e-5f

// two-level counting sort geometry
#define BKT_SH 8
#define BKT_SZ 256
#define NBKT   ((N_NODES + BKT_SZ - 1) / BKT_SZ)  // 196
#define CHKE   4096
#define NCHK   ((N_EDGES + CHKE - 1) / CHKE)      // 245
#define CNTM   (NBKT * NCHK)                      // 48020
#define NB2    ((CNTM + 255) / 256)               // 188

__device__ __forceinline__ void atomAddF(float* p, float v) {
    __hip_atomic_fetch_add(p, v, __ATOMIC_RELAXED, __HIP_MEMORY_SCOPE_AGENT);
}

__device__ __forceinline__ unsigned short f2bf(float f) {
    unsigned int u = __float_as_uint(f);
    u += 0x7fffu + ((u >> 16) & 1u);
    return (unsigned short)(u >> 16);
}
__device__ __forceinline__ float bf2f(unsigned short s) {
    return __uint_as_float(((unsigned int)s) << 16);
}
__device__ __forceinline__ float4 bf4(ushort4 u) {
    return make_float4(bf2f(u.x), bf2f(u.y), bf2f(u.z), bf2f(u.w));
}

// h(bf16) = x @ xW + xb
__global__ void k_input(const float* __restrict__ x, const float* __restrict__ xW,
                        const float* __restrict__ xb, unsigned short* __restrict__ h) {
    int gid = blockIdx.x * 256 + threadIdx.x;
    if (gid >= N_NODES * EMB) return;
    int n = gid >> 6, f = gid & 63;
    float acc = xb[f];
#pragma unroll
    for (int k = 0; k < XFD; ++k) acc = fmaf(x[n * XFD + k], xW[k * EMB + f], acc);
    h[gid] = f2bf(acc);
}

// ---- phase A: per-chunk coarse-bucket histogram ----
__global__ __launch_bounds__(256) void k_binA(const int* __restrict__ dst,
                                              int* __restrict__ cntmat) {
    __shared__ int hist[NBKT];
    int tid = threadIdx.x, c = blockIdx.x;
    for (int i = tid; i < NBKT; i += 256) hist[i] = 0;
    __syncthreads();
    int e0 = c * CHKE, e1 = min(e0 + CHKE, N_EDGES);
    for (int i = e0 + tid; i < e1; i += 256) atomicAdd(&hist[dst[i] >> BKT_SH], 1);
    __syncthreads();
    for (int b = tid; b < NBKT; b += 256) cntmat[b * NCHK + c] = hist[b];
}

// ---- 3-phase multi-block exclusive scan ----
__global__ __launch_bounds__(256) void k_gscanA(const int* __restrict__ in, int n,
                                                int* __restrict__ bsum) {
    int tid = threadIdx.x, lane = tid & 63, wid = tid >> 6;
    int i = blockIdx.x * 256 + tid;
    int v = (i < n) ? in[i] : 0;
#pragma unroll
    for (int off = 32; off; off >>= 1) v += __shfl_down(v, off);
    __shared__ int ws[4];
    if (lane == 0) ws[wid] = v;
    __syncthreads();
    if (tid == 0) bsum[blockIdx.x] = ws[0] + ws[1] + ws[2] + ws[3];
}

__global__ __launch_bounds__(256) void k_gscanB(const int* __restrict__ bsum, int nb,
                                                int* __restrict__ boff) {
    int tid = threadIdx.x, lane = tid & 63, wid = tid >> 6;
    int v = (tid < nb) ? bsum[tid] : 0;
    int x = v;
#pragma unroll
    for (int off = 1; off < 64; off <<= 1) {
        int y = __shfl_up(x, off);
        if (lane >= off) x += y;
    }
    __shared__ int wtot[4];
    if (lane == 63) wtot[wid] = x;
    __syncthreads();
    int woff = 0;
    for (int w = 0; w < wid; ++w) woff += wtot[w];
    if (tid < nb) boff[tid] = woff + x - v;
}

__global__ __launch_bounds__(256) void k_gscanC(const int* __restrict__ in, int n,
                                                const int* __restrict__ boff,
                                                int* __restrict__ out) {
    int tid = threadIdx.x, lane = tid & 63, wid = tid >> 6;
    int i = blockIdx.x * 256 + tid;
    int v = (i < n) ? in[i] : 0;
    int x = v;
#pragma unroll
    for (int off = 1; off < 64; off <<= 1) {
        int y = __shfl_up(x, off);
        if (lane >= off) x += y;
    }
    __shared__ int wtot[4];
    if (lane == 63) wtot[wid] = x;
    __syncthreads();
    int woff = boff[blockIdx.x];
    for (int w = 0; w < wid; ++w) woff += wtot[w];
    if (i < n) out[i] = woff + x - v;
}

// ---- phase C: coarse scatter of packed {src, d_local<<20|eid} ----
__global__ __launch_bounds__(256) void k_binC(const int* __restrict__ src,
                                              const int* __restrict__ dst,
                                              const int* __restrict__ off2,
                                              int2* __restrict__ bufSD) {
    __shared__ int cur[NBKT];
    int tid = threadIdx.x, c = blockIdx.x;
    for (int b = tid; b < NBKT; b += 256) cur[b] = off2[b * NCHK + c];
    __syncthreads();
    int e0 = c * CHKE, e1 = min(e0 + CHKE, N_EDGES);
    for (int i = e0 + tid; i < e1; i += 256) {
        int d = dst[i];
        int b = d >> BKT_SH;
        int p = atomicAdd(&cur[b], 1);
        bufSD[p] = make_int2(src[i], ((d & (BKT_SZ - 1)) << 20) | i);
    }
}

// ---- phase D: per-bucket fine sort -> csr + csrE + rowstart ----
__global__ __launch_bounds__(256) void k_binD(const int2* __restrict__ bufSD,
                                              const int* __restrict__ off2,
                                              int* __restrict__ csr,
                                              int* __restrict__ csrE,
                                              int* __restrict__ rowstart) {
    __shared__ int hist[BKT_SZ];
    __shared__ int cur[BKT_SZ];
    __shared__ int wtot[4];
    int tid = threadIdx.x, b = blockIdx.x;
    int bstart = off2[b * NCHK];
    int bend = (b + 1 < NBKT) ? off2[(b + 1) * NCHK] : N_EDGES;
    hist[tid] = 0;
    __syncthreads();
    for (int j = bstart + tid; j < bend; j += 256)
        atomicAdd(&hist[bufSD[j].y >> 20], 1);
    __syncthreads();
    int lane = tid & 63, wid = tid >> 6;
    int v = hist[tid], x = v;
#pragma unroll
    for (int off = 1; off < 64; off <<= 1) {
        int y = __shfl_up(x, off);
        if (lane >= off) x += y;
    }
    if (lane == 63) wtot[wid] = x;
    __syncthreads();
    int woff = 0;
    for (int w = 0; w < wid; ++w) woff += wtot[w];
    int ex = woff + x - v;
    cur[tid] = ex;
    int node = b * BKT_SZ + tid;
    if (node < N_NODES) rowstart[node] = bstart + ex;
    if (b == NBKT - 1 && tid == 0) rowstart[N_NODES] = N_EDGES;
    __syncthreads();
    for (int j = bstart + tid; j < bend; j += 256) {
        int2 t = bufSD[j];
        int local = t.y >> 20;
        int p = atomicAdd(&cur[local], 1);
        csr[bstart + p] = t.x;
        csrE[bstart + p] = t.y & 0xFFFFF;
    }
}

// aggE[n] = sum of ea over in-edges (wave/node, full-device concurrency)
__global__ __launch_bounds__(256) void k_aggE(const int* __restrict__ rowstart,
                                              const int* __restrict__ csrE,
                                              const float* __restrict__ ea,
                                              float* __restrict__ aggE) {
    int wid = (blockIdx.x * 256 + threadIdx.x) >> 6;
    int lane = threadIdx.x & 63;
    if (wid >= N_NODES) return;
    int j0 = rowstart[wid], j1 = rowstart[wid + 1];
    float s0 = 0.f, s1 = 0.f, s2 = 0.f, s3 = 0.f, s4 = 0.f;
    for (int j = j0 + lane; j < j1; j += 64) {
        int e = csrE[j];
        const float* p = ea + (size_t)e * EFD;
        s0 += p[0]; s1 += p[1]; s2 += p[2]; s3 += p[3]; s4 += p[4];
    }
#pragma unroll
    for (int off = 32; off; off >>= 1) {
        s0 += __shfl_down(s0, off);
        s1 += __shfl_down(s1, off);
        s2 += __shfl_down(s2, off);
        s3 += __shfl_down(s3, off);
        s4 += __shfl_down(s4, off);
    }
    if (lane == 0) {
        float* o = aggE + (size_t)wid * EFD;
        o[0] = s0; o[1] = s1; o[2] = s2; o[3] = s3; o[4] = s4;
    }
}

// agg(f32): wave handles 4 consecutive nodes — eW/eb register loads amortized
__global__ __launch_bounds__(256) void k_agg(const unsigned short* __restrict__ h,
                                             float* __restrict__ agg,
                                             const int* __restrict__ rowstart,
                                             const int* __restrict__ csr,
                                             const float* __restrict__ aggE,
                                             const float* __restrict__ eWl,
                                             const float* __restrict__ ebl) {
    int wave = (blockIdx.x * 256 + threadIdx.x) >> 6;
    int lane = threadIdx.x & 63;
    int nbase = wave * 4;
    if (nbase >= N_NODES) return;
    int lg = lane >> 4, lq = lane & 15;
    const ushort4* hb = (const ushort4*)h;
    // wave-invariant loads (amortized over 4 nodes)
    const float4* eW4 = (const float4*)eWl;
    float4 ew0 = eW4[lq], ew1 = eW4[16 + lq], ew2 = eW4[32 + lq],
           ew3 = eW4[48 + lq], ew4 = eW4[64 + lq];
    float4 eb4 = ((const float4*)ebl)[lq];
    int nend = min(nbase + 4, N_NODES);
    for (int n = nbase; n < nend; ++n) {
        int j0 = rowstart[n], j1 = rowstart[n + 1];
        float4 acc = make_float4(0.f, 0.f, 0.f, 0.f);
        int j = j0;
        while (j < j1) {
            int take = j1 - j;
            if (take > 64) take = 64;
            int myid = (lane < take) ? csr[j + lane] : 0;
            int nt = (take + 3) >> 2;
            int t = 0;
            for (; t + 4 <= nt; t += 4) {
                int e0 = t * 4 + lg, e1 = e0 + 4, e2 = e0 + 8, e3 = e0 + 12;
                int s0 = __shfl(myid, e0), s1 = __shfl(myid, e1),
                    s2 = __shfl(myid, e2), s3 = __shfl(myid, e3);
                float4 v0 = bf4(hb[(size_t)s0 * 16 + lq]);
                float4 v1 = bf4(hb[(size_t)s1 * 16 + lq]);
                float4 v2 = bf4(hb[(size_t)s2 * 16 + lq]);
                float4 v3 = bf4(hb[(size_t)s3 * 16 + lq]);
                if (e0 < take) { acc.x += v0.x; acc.y += v0.y; acc.z += v0.z; acc.w += v0.w; }
                if (e1 < take) { acc.x += v1.x; acc.y += v1.y; acc.z += v1.z; acc.w += v1.w; }
                if (e2 < take) { acc.x += v2.x; acc.y += v2.y; acc.z += v2.z; acc.w += v2.w; }
                if (e3 < take) { acc.x += v3.x; acc.y += v3.y; acc.z += v3.z; acc.w += v3.w; }
            }
            for (; t < nt; ++t) {
                int e = t * 4 + lg;
                int s = __shfl(myid, e);
                float4 v = bf4(hb[(size_t)s * 16 + lq]);
                if (e < take) { acc.x += v.x; acc.y += v.y; acc.z += v.z; acc.w += v.w; }
            }
            j += take;
        }
        acc.x += __shfl_xor(acc.x, 16); acc.y += __shfl_xor(acc.y, 16);
        acc.z += __shfl_xor(acc.z, 16); acc.w += __shfl_xor(acc.w, 16);
        acc.x += __shfl_xor(acc.x, 32); acc.y += __shfl_xor(acc.y, 32);
        acc.z += __shfl_xor(acc.z, 32); acc.w += __shfl_xor(acc.w, 32);
        float a0 = aggE[n * 5 + 0], a1 = aggE[n * 5 + 1], a2 = aggE[n * 5 + 2],
              a3 = aggE[n * 5 + 3], a4 = aggE[n * 5 + 4];
        float c0 = a0 + 8.f;
        float ce = (float)(j1 - j0) + 1.f;
        float4 bb = bf4(hb[(size_t)n * 16 + lq]);  // self term
        bb.x = fmaf(c0, ew0.x, bb.x); bb.y = fmaf(c0, ew0.y, bb.y);
        bb.z = fmaf(c0, ew0.z, bb.z); bb.w = fmaf(c0, ew0.w, bb.w);
        bb.x = fmaf(a1, ew1.x, bb.x); bb.y = fmaf(a1, ew1.y, bb.y);
        bb.z = fmaf(a1, ew1.z, bb.z); bb.w = fmaf(a1, ew1.w, bb.w);
        bb.x = fmaf(a2, ew2.x, bb.x); bb.y = fmaf(a2, ew2.y, bb.y);
        bb.z = fmaf(a2, ew2.z, bb.z); bb.w = fmaf(a2, ew2.w, bb.w);
        bb.x = fmaf(a3, ew3.x, bb.x); bb.y = fmaf(a3, ew3.y, bb.y);
        bb.z = fmaf(a3, ew3.z, bb.z); bb.w = fmaf(a3, ew3.w, bb.w);
        bb.x = fmaf(a4, ew4.x, bb.x); bb.y = fmaf(a4, ew4.y, bb.y);
        bb.z = fmaf(a4, ew4.z, bb.z); bb.w = fmaf(a4, ew4.w, bb.w);
        bb.x = fmaf(ce, eb4.x, bb.x); bb.y = fmaf(ce, eb4.y, bb.y);
        bb.z = fmaf(ce, eb4.z, bb.z); bb.w = fmaf(ce, eb4.w, bb.w);
        if (lg == 0) {
            ((float4*)agg)[(size_t)n * 16 + lq] =
                make_float4(acc.x + bb.x, acc.y + bb.y, acc.z + bb.z, acc.w + bb.w);
        }
    }
}

// Fused MLP: h2 = relu(agg@W1+b1)@W2 + b2, + BN stats. hidden lives in LDS only.
// 64-node tile; weights/act tiles bf16 in LDS (59.6KB -> 2 blocks/CU).
__global__ __launch_bounds__(256) void k_mlp(const float* __restrict__ agg,
                                             float* __restrict__ h2,
                                             const float* __restrict__ W1l,
                                             const float* __restrict__ b1l,
                                             const float* __restrict__ W2l,
                                             const float* __restrict__ b2l,
                                             float* __restrict__ stats) {
    __shared__ unsigned short w1s[64 * 128];   // [k*128+j] bf16
    __shared__ unsigned short w2s[128 * 64];   // [k*64+f]  bf16
    __shared__ unsigned short asT[64 * 68];    // [k*68+m]  bf16 (transposed agg tile)
    __shared__ unsigned short hidT[128 * 68];  // [j*68+m]  bf16 (transposed hidden)
    __shared__ float b1s[128];
    __shared__ float b2s[64];
    int tid = threadIdx.x;
    int n0 = blockIdx.x * 64;
    // stage weights -> bf16 LDS
    const float4* wg1 = (const float4*)W1l;
    const float4* wg2 = (const float4*)W2l;
    ushort4* w1v = (ushort4*)w1s;
    ushort4* w2v = (ushort4*)w2s;
#pragma unroll
    for (int i = 0; i < 8; ++i) {
        float4 v1 = wg1[tid + i * 256];
        w1v[tid + i * 256] = make_ushort4(f2bf(v1.x), f2bf(v1.y), f2bf(v1.z), f2bf(v1.w));
        float4 v2 = wg2[tid + i * 256];
        w2v[tid + i * 256] = make_ushort4(f2bf(v2.x), f2bf(v2.y), f2bf(v2.z), f2bf(v2.w));
    }
    if (tid < 128) b1s[tid] = b1l[tid];
    if (tid < 64) b2s[tid] = b2l[tid];
    // stage agg tile transposed -> asT[k][m]
    const float4* ag4 = (const float4*)agg;
#pragma unroll
    for (int i = 0; i < 4; ++i) {
        int idx = tid + i * 256;  // 1024 float4s: m=idx>>4, kq=idx&15
        int m = idx >> 4, kq = idx & 15;
        int nn = n0 + m;
        float4 v = make_float4(0.f, 0.f, 0.f, 0.f);
        if (nn < N_NODES) v = ag4[(size_t)nn * 16 + kq];
        asT[(kq * 4 + 0) * 68 + m] = f2bf(v.x);
        asT[(kq * 4 + 1) * 68 + m] = f2bf(v.y);
        asT[(kq * 4 + 2) * 68 + m] = f2bf(v.z);
        asT[(kq * 4 + 3) * 68 + m] = f2bf(v.w);
    }
    __syncthreads();
    // phase 1: hidden[64 nodes][128] = relu(agg @ W1 + b1) -> hidT bf16
    {
        int j0 = (tid & 31) * 4;
        int m0 = (tid >> 5) * 8;
        float acc1[8][4] = {};
#pragma unroll 4
        for (int k = 0; k < 64; ++k) {
            float4 w = bf4(((const ushort4*)w1s)[k * 32 + (j0 >> 2)]);
            float4 av0 = bf4(*(const ushort4*)&asT[k * 68 + m0]);
            float4 av1 = bf4(*(const ushort4*)&asT[k * 68 + m0 + 4]);
            float a[8] = {av0.x, av0.y, av0.z, av0.w, av1.x, av1.y, av1.z, av1.w};
#pragma unroll
            for (int i = 0; i < 8; ++i) {
                acc1[i][0] = fmaf(a[i], w.x, acc1[i][0]);
                acc1[i][1] = fmaf(a[i], w.y, acc1[i][1]);
                acc1[i][2] = fmaf(a[i], w.z, acc1[i][2]);
                acc1[i][3] = fmaf(a[i], w.w, acc1[i][3]);
            }
        }
#pragma unroll
        for (int c = 0; c < 4; ++c) {
            float bv = b1s[j0 + c];
            ushort4 o1, o2;
            o1.x = f2bf(fmaxf(acc1[0][c] + bv, 0.f));
            o1.y = f2bf(fmaxf(acc1[1][c] + bv, 0.f));
            o1.z = f2bf(fmaxf(acc1[2][c] + bv, 0.f));
            o1.w = f2bf(fmaxf(acc1[3][c] + bv, 0.f));
            o2.x = f2bf(fmaxf(acc1[4][c] + bv, 0.f));
            o2.y = f2bf(fmaxf(acc1[5][c] + bv, 0.f));
            o2.z = f2bf(fmaxf(acc1[6][c] + bv, 0.f));
            o2.w = f2bf(fmaxf(acc1[7][c] + bv, 0.f));
            *(ushort4*)&hidT[(j0 + c) * 68 + m0] = o1;
            *(ushort4*)&hidT[(j0 + c) * 68 + m0 + 4] = o2;
        }
    }
    __syncthreads();
    // phase 2: h2 = hidden @ W2 + b2 (+ stats)
    int f0 = (tid & 15) * 4;
    int m0p = (tid >> 4) * 4;
    float acc2[4][4] = {};
#pragma unroll 4
    for (int k = 0; k < 128; ++k) {
        float4 w = bf4(((const ushort4*)w2s)[k * 16 + (f0 >> 2)]);
        float4 a = bf4(*(const ushort4*)&hidT[k * 68 + m0p]);
        acc2[0][0] = fmaf(a.x, w.x, acc2[0][0]); acc2[0][1] = fmaf(a.x, w.y, acc2[0][1]);
        acc2[0][2] = fmaf(a.x, w.z, acc2[0][2]); acc2[0][3] = fmaf(a.x, w.w, acc2[0][3]);
        acc2[1][0] = fmaf(a.y, w.x, acc2[1][0]); acc2[1][1] = fmaf(a.y, w.y, acc2[1][1]);
        acc2[1][2] = fmaf(a.y, w.z, acc2[1][2]); acc2[1][3] = fmaf(a.y, w.w, acc2[1][3]);
        acc2[2][0] = fmaf(a.z, w.x, acc2[2][0]); acc2[2][1] = fmaf(a.z, w.y, acc2[2][1]);
        acc2[2][2] = fmaf(a.z, w.z, acc2[2][2]); acc2[2][3] = fmaf(a.z, w.w, acc2[2][3]);
        acc2[3][0] = fmaf(a.w, w.x, acc2[3][0]); acc2[3][1] = fmaf(a.w, w.y, acc2[3][1]);
        acc2[3][2] = fmaf(a.w, w.z, acc2[3][2]); acc2[3][3] = fmaf(a.w, w.w, acc2[3][3]);
    }
    float sf[4] = {0.f, 0.f, 0.f, 0.f}, qf[4] = {0.f, 0.f, 0.f, 0.f};
#pragma unroll
    for (int i = 0; i < 4; ++i) {
        int nn = n0 + m0p + i;
        if (nn < N_NODES) {
            float v0 = acc2[i][0] + b2s[f0 + 0];
            float v1 = acc2[i][1] + b2s[f0 + 1];
            float v2 = acc2[i][2] + b2s[f0 + 2];
            float v3 = acc2[i][3] + b2s[f0 + 3];
            *(float4*)&h2[(size_t)nn * EMB + f0] = make_float4(v0, v1, v2, v3);
            sf[0] += v0; sf[1] += v1; sf[2] += v2; sf[3] += v3;
            qf[0] = fmaf(v0, v0, qf[0]); qf[1] = fmaf(v1, v1, qf[1]);
            qf[2] = fmaf(v2, v2, qf[2]); qf[3] = fmaf(v3, v3, qf[3]);
        }
    }
    __syncthreads();  // done reading hidT; reuse as reduction scratch
    float* red = (float*)hidT;  // needs 2048 floats = 8KB <= 17.4KB
    int mg = tid >> 4;
#pragma unroll
    for (int j = 0; j < 4; ++j) {
        red[mg * 64 + f0 + j] = sf[j];
        red[1024 + mg * 64 + f0 + j] = qf[j];
    }
    __syncthreads();
    if (tid < 64) {
        float s = 0.f, q = 0.f;
#pragma unroll
        for (int m = 0; m < 16; ++m) {
            s += red[m * 64 + tid];
            q += red[1024 + m * 64 + tid];
        }
        atomAddF(&stats[tid], s);
        atomAddF(&stats[64 + tid], q);
    }
}

// BN apply + ELU (layers 0,1): h(bf16) = elu(bn(h2))
__global__ void k_bn(const float* __restrict__ h2, unsigned short* __restrict__ h,
                     const float* __restrict__ stats, const float* __restrict__ gam,
                     const float* __restrict__ bet) {
    int gid = blockIdx.x * 256 + threadIdx.x;
    if (gid >= N_NODES * EMB) return;
    int f = gid & 63;
    const float invN = 1.f / (float)N_NODES;
    float mean = stats[f] * invN;
    float var = stats[64 + f] * invN - mean * mean;
    float inv = rsqrtf(var + BN_EPS);
    float v = (h2[gid] - mean) * inv * gam[f] + bet[f];
    h[gid] = f2bf(v > 0.f ? v : expm1f(v));
}

// last layer: BN only for the 250 super-nodes (h2 stays fp32)
__global__ void k_bnout(const float* __restrict__ h2, const int* __restrict__ last,
                        const float* __restrict__ stats, const float* __restrict__ gam,
                        const float* __restrict__ bet, float* __restrict__ out) {
    int gid = blockIdx.x * 256 + threadIdx.x;
    if (gid >= NGRAPH * EMB) return;
    int b = gid >> 6, f = gid & 63;
    const float invN = 1.f / (float)N_NODES;
    float mean = stats[f] * invN;
    float var = stats[64 + f] * invN - mean * mean;
    float inv = rsqrtf(var + BN_EPS);
    out[gid] = (h2[last[b] * EMB + f] - mean) * inv * gam[f] + bet[f];
}

extern "C" void kernel_launch(void* const* d_in, const int* in_sizes, int n_in,
                              void* d_out, int out_size, void* d_ws, size_t ws_size,
                              hipStream_t stream) {
    const float* x   = (const float*)d_in[0];
    const float* ea  = (const float*)d_in[1];
    const int*   eidx= (const int*)d_in[2];
    const int*   last= (const int*)d_in[3];
    const float* xW  = (const float*)d_in[4];
    const float* xb  = (const float*)d_in[5];
    const float* eW  = (const float*)d_in[6];
    const float* eb  = (const float*)d_in[7];
    const float* W1  = (const float*)d_in[8];
    const float* b1  = (const float*)d_in[9];
    const float* W2  = (const float*)d_in[10];
    const float* b2  = (const float*)d_in[11];
    const float* gam = (const float*)d_in[12];
    const float* bet = (const float*)d_in[13];
    float* out = (float*)d_out;

    const int* srcI = eidx;
    const int* dstI = eidx + N_EDGES;

    float* hslot  = (float*)d_ws;              // h bf16 uses half this slot
    float* agg    = hslot + N_NODES * EMB;     // N*64 f32 (h2 in loop)
    float* hidslot= agg + N_NODES * EMB;       // scratch (csrE alias)
    float* aggE   = hidslot + N_NODES * HID;
    float* stats  = aggE + NBKT * BKT_SZ * EFD;
    int* rowstart = (int*)(stats + NLAYER * 2 * EMB);
    int* csr      = rowstart + N_NODES + 1;
    int* cntmat   = csr + N_EDGES;
    int* off2     = cntmat + CNTM;
    int* bsum     = off2 + CNTM;
    int* boff     = bsum + NB2;
    unsigned short* h = (unsigned short*)hslot;
    int2* bufSD   = (int2*)agg;                // alias, dead before loop
    int*  csrE    = (int*)hidslot;             // alias, dead after aggE

    hipMemsetAsync(stats, 0, NLAYER * 2 * EMB * sizeof(float), stream);

    k_input<<<(N_NODES * EMB + 255) / 256, 256, 0, stream>>>(x, xW, xb, h);
    k_binA<<<NCHK, 256, 0, stream>>>(dstI, cntmat);
    k_gscanA<<<NB2, 256, 0, stream>>>(cntmat, CNTM, bsum);
    k_gscanB<<<1, 256, 0, stream>>>(bsum, NB2, boff);
    k_gscanC<<<NB2, 256, 0, stream>>>(cntmat, CNTM, boff, off2);
    k_binC<<<NCHK, 256, 0, stream>>>(srcI, dstI, off2, bufSD);
    k_binD<<<NBKT, 256, 0, stream>>>(bufSD, off2, csr, csrE, rowstart);
    k_aggE<<<(N_NODES * 64 + 255) / 256, 256, 0, stream>>>(rowstart, csrE, ea, aggE);

    const int aggBlocks = ((N_NODES + 3) / 4 * 64 + 255) / 256;  // 4 nodes/wave
    const int mlpBlocks = (N_NODES + 63) / 64;
    for (int l = 0; l < NLAYER; ++l) {
        k_agg<<<aggBlocks, 256, 0, stream>>>(
            h, agg, rowstart, csr, aggE, eW + l * EFD * EMB, eb + l * EMB);
        k_mlp<<<mlpBlocks, 256, 0, stream>>>(agg, agg, W1 + l * EMB * HID, b1 + l * HID,
                                             W2 + l * HID * EMB, b2 + l * EMB,
                                             stats + l * 2 * EMB);
        if (l < NLAYER - 1) {
            k_bn<<<(N_NODES * EMB + 255) / 256, 256, 0, stream>>>(
                agg, h, stats + l * 2 * EMB, gam + l * EMB, bet + l * EMB);
        } else {
            k_bnout<<<(NGRAPH * EMB + 255) / 256, 256, 0, stream>>>(
                agg, last, stats + l * 2 * EMB, gam + l * EMB, bet + l * EMB, out);
        }
    }
}

// Round 10
// 393.178 us; speedup vs baseline: 1.1509x; 1.0185x over previous
//
#include <hip/hip_runtime.h>

#define N_NODES 50000
#define N_EDGES 1000000
#define EMB     64
#define HID     128
#define NLAYER  3
#define NGRAPH  250
#define XFD     7
#define EFD     5
#define BN_EPS  1e-5f

// two-level counting sort geometry
#define BKT_SH 8
#define BKT_SZ 256
#define NBKT   ((N_NODES + BKT_SZ - 1) / BKT_SZ)  // 196
#define CHKE   4096
#define NCHK   ((N_EDGES + CHKE - 1) / CHKE)      // 245
#define CNTM   (NBKT * NCHK)                      // 48020
#define NB2    ((CNTM + 255) / 256)               // 188

__device__ __forceinline__ void atomAddF(float* p, float v) {
    __hip_atomic_fetch_add(p, v, __ATOMIC_RELAXED, __HIP_MEMORY_SCOPE_AGENT);
}

__device__ __forceinline__ unsigned short f2bf(float f) {
    unsigned int u = __float_as_uint(f);
    u += 0x7fffu + ((u >> 16) & 1u);
    return (unsigned short)(u >> 16);
}
__device__ __forceinline__ float bf2f(unsigned short s) {
    return __uint_as_float(((unsigned int)s) << 16);
}
__device__ __forceinline__ float4 bf4(ushort4 u) {
    return make_float4(bf2f(u.x), bf2f(u.y), bf2f(u.z), bf2f(u.w));
}

// h(bf16) = x @ xW + xb
__global__ void k_input(const float* __restrict__ x, const float* __restrict__ xW,
                        const float* __restrict__ xb, unsigned short* __restrict__ h) {
    int gid = blockIdx.x * 256 + threadIdx.x;
    if (gid >= N_NODES * EMB) return;
    int n = gid >> 6, f = gid & 63;
    float acc = xb[f];
#pragma unroll
    for (int k = 0; k < XFD; ++k) acc = fmaf(x[n * XFD + k], xW[k * EMB + f], acc);
    h[gid] = f2bf(acc);
}

// ---- phase A: per-chunk coarse-bucket histogram ----
__global__ __launch_bounds__(256) void k_binA(const int* __restrict__ dst,
                                              int* __restrict__ cntmat) {
    __shared__ int hist[NBKT];
    int tid = threadIdx.x, c = blockIdx.x;
    for (int i = tid; i < NBKT; i += 256) hist[i] = 0;
    __syncthreads();
    int e0 = c * CHKE, e1 = min(e0 + CHKE, N_EDGES);
    for (int i = e0 + tid; i < e1; i += 256) atomicAdd(&hist[dst[i] >> BKT_SH], 1);
    __syncthreads();
    for (int b = tid; b < NBKT; b += 256) cntmat[b * NCHK + c] = hist[b];
}

// ---- 3-phase multi-block exclusive scan ----
__global__ __launch_bounds__(256) void k_gscanA(const int* __restrict__ in, int n,
                                                int* __restrict__ bsum) {
    int tid = threadIdx.x, lane = tid & 63, wid = tid >> 6;
    int i = blockIdx.x * 256 + tid;
    int v = (i < n) ? in[i] : 0;
#pragma unroll
    for (int off = 32; off; off >>= 1) v += __shfl_down(v, off);
    __shared__ int ws[4];
    if (lane == 0) ws[wid] = v;
    __syncthreads();
    if (tid == 0) bsum[blockIdx.x] = ws[0] + ws[1] + ws[2] + ws[3];
}

__global__ __launch_bounds__(256) void k_gscanB(const int* __restrict__ bsum, int nb,
                                                int* __restrict__ boff) {
    int tid = threadIdx.x, lane = tid & 63, wid = tid >> 6;
    int v = (tid < nb) ? bsum[tid] : 0;
    int x = v;
#pragma unroll
    for (int off = 1; off < 64; off <<= 1) {
        int y = __shfl_up(x, off);
        if (lane >= off) x += y;
    }
    __shared__ int wtot[4];
    if (lane == 63) wtot[wid] = x;
    __syncthreads();
    int woff = 0;
    for (int w = 0; w < wid; ++w) woff += wtot[w];
    if (tid < nb) boff[tid] = woff + x - v;
}

__global__ __launch_bounds__(256) void k_gscanC(const int* __restrict__ in, int n,
                                                const int* __restrict__ boff,
                                                int* __restrict__ out) {
    int tid = threadIdx.x, lane = tid & 63, wid = tid >> 6;
    int i = blockIdx.x * 256 + tid;
    int v = (i < n) ? in[i] : 0;
    int x = v;
#pragma unroll
    for (int off = 1; off < 64; off <<= 1) {
        int y = __shfl_up(x, off);
        if (lane >= off) x += y;
    }
    __shared__ int wtot[4];
    if (lane == 63) wtot[wid] = x;
    __syncthreads();
    int woff = boff[blockIdx.x];
    for (int w = 0; w < wid; ++w) woff += wtot[w];
    if (i < n) out[i] = woff + x - v;
}

// ---- phase C: coarse scatter of packed {src, d_local<<20|eid} ----
__global__ __launch_bounds__(256) void k_binC(const int* __restrict__ src,
                                              const int* __restrict__ dst,
                                              const int* __restrict__ off2,
                                              int2* __restrict__ bufSD) {
    __shared__ int cur[NBKT];
    int tid = threadIdx.x, c = blockIdx.x;
    for (int b = tid; b < NBKT; b += 256) cur[b] = off2[b * NCHK + c];
    __syncthreads();
    int e0 = c * CHKE, e1 = min(e0 + CHKE, N_EDGES);
    for (int i = e0 + tid; i < e1; i += 256) {
        int d = dst[i];
        int b = d >> BKT_SH;
        int p = atomicAdd(&cur[b], 1);
        bufSD[p] = make_int2(src[i], ((d & (BKT_SZ - 1)) << 20) | i);
    }
}

// ---- phase D: per-bucket fine sort -> csr + csrE + rowstart ----
__global__ __launch_bounds__(256) void k_binD(const int2* __restrict__ bufSD,
                                              const int* __restrict__ off2,
                                              int* __restrict__ csr,
                                              int* __restrict__ csrE,
                                              int* __restrict__ rowstart) {
    __shared__ int hist[BKT_SZ];
    __shared__ int cur[BKT_SZ];
    __shared__ int wtot[4];
    int tid = threadIdx.x, b = blockIdx.x;
    int bstart = off2[b * NCHK];
    int bend = (b + 1 < NBKT) ? off2[(b + 1) * NCHK] : N_EDGES;
    hist[tid] = 0;
    __syncthreads();
    for (int j = bstart + tid; j < bend; j += 256)
        atomicAdd(&hist[bufSD[j].y >> 20], 1);
    __syncthreads();
    int lane = tid & 63, wid = tid >> 6;
    int v = hist[tid], x = v;
#pragma unroll
    for (int off = 1; off < 64; off <<= 1) {
        int y = __shfl_up(x, off);
        if (lane >= off) x += y;
    }
    if (lane == 63) wtot[wid] = x;
    __syncthreads();
    int woff = 0;
    for (int w = 0; w < wid; ++w) woff += wtot[w];
    int ex = woff + x - v;
    cur[tid] = ex;
    int node = b * BKT_SZ + tid;
    if (node < N_NODES) rowstart[node] = bstart + ex;
    if (b == NBKT - 1 && tid == 0) rowstart[N_NODES] = N_EDGES;
    __syncthreads();
    for (int j = bstart + tid; j < bend; j += 256) {
        int2 t = bufSD[j];
        int local = t.y >> 20;
        int p = atomicAdd(&cur[local], 1);
        csr[bstart + p] = t.x;
        csrE[bstart + p] = t.y & 0xFFFFF;
    }
}

// aggE[n] = sum of ea over in-edges (wave/node, full-device concurrency)
__global__ __launch_bounds__(256) void k_aggE(const int* __restrict__ rowstart,
                                              const int* __restrict__ csrE,
                                              const float* __restrict__ ea,
                                              float* __restrict__ aggE) {
    int wid = (blockIdx.x * 256 + threadIdx.x) >> 6;
    int lane = threadIdx.x & 63;
    if (wid >= N_NODES) return;
    int j0 = rowstart[wid], j1 = rowstart[wid + 1];
    float s0 = 0.f, s1 = 0.f, s2 = 0.f, s3 = 0.f, s4 = 0.f;
    for (int j = j0 + lane; j < j1; j += 64) {
        int e = csrE[j];
        const float* p = ea + (size_t)e * EFD;
        s0 += p[0]; s1 += p[1]; s2 += p[2]; s3 += p[3]; s4 += p[4];
    }
#pragma unroll
    for (int off = 32; off; off >>= 1) {
        s0 += __shfl_down(s0, off);
        s1 += __shfl_down(s1, off);
        s2 += __shfl_down(s2, off);
        s3 += __shfl_down(s3, off);
        s4 += __shfl_down(s4, off);
    }
    if (lane == 0) {
        float* o = aggE + (size_t)wid * EFD;
        o[0] = s0; o[1] = s1; o[2] = s2; o[3] = s3; o[4] = s4;
    }
}

// agg(f32): wave handles 4 consecutive nodes
__global__ __launch_bounds__(256) void k_agg(const unsigned short* __restrict__ h,
                                             float* __restrict__ agg,
                                             const int* __restrict__ rowstart,
                                             const int* __restrict__ csr,
                                             const float* __restrict__ aggE,
                                             const float* __restrict__ eWl,
                                             const float* __restrict__ ebl) {
    int wave = (blockIdx.x * 256 + threadIdx.x) >> 6;
    int lane = threadIdx.x & 63;
    int nbase = wave * 4;
    if (nbase >= N_NODES) return;
    int lg = lane >> 4, lq = lane & 15;
    const ushort4* hb = (const ushort4*)h;
    const float4* eW4 = (const float4*)eWl;
    float4 ew0 = eW4[lq], ew1 = eW4[16 + lq], ew2 = eW4[32 + lq],
           ew3 = eW4[48 + lq], ew4 = eW4[64 + lq];
    float4 eb4 = ((const float4*)ebl)[lq];
    int nend = min(nbase + 4, N_NODES);
    for (int n = nbase; n < nend; ++n) {
        int j0 = rowstart[n], j1 = rowstart[n + 1];
        float4 acc = make_float4(0.f, 0.f, 0.f, 0.f);
        int j = j0;
        while (j < j1) {
            int take = j1 - j;
            if (take > 64) take = 64;
            int myid = (lane < take) ? csr[j + lane] : 0;
            int nt = (take + 3) >> 2;
            int t = 0;
            for (; t + 4 <= nt; t += 4) {
                int e0 = t * 4 + lg, e1 = e0 + 4, e2 = e0 + 8, e3 = e0 + 12;
                int s0 = __shfl(myid, e0), s1 = __shfl(myid, e1),
                    s2 = __shfl(myid, e2), s3 = __shfl(myid, e3);
                float4 v0 = bf4(hb[(size_t)s0 * 16 + lq]);
                float4 v1 = bf4(hb[(size_t)s1 * 16 + lq]);
                float4 v2 = bf4(hb[(size_t)s2 * 16 + lq]);
                float4 v3 = bf4(hb[(size_t)s3 * 16 + lq]);
                if (e0 < take) { acc.x += v0.x; acc.y += v0.y; acc.z += v0.z; acc.w += v0.w; }
                if (e1 < take) { acc.x += v1.x; acc.y += v1.y; acc.z += v1.z; acc.w += v1.w; }
                if (e2 < take) { acc.x += v2.x; acc.y += v2.y; acc.z += v2.z; acc.w += v2.w; }
                if (e3 < take) { acc.x += v3.x; acc.y += v3.y; acc.z += v3.z; acc.w += v3.w; }
            }
            for (; t < nt; ++t) {
                int e = t * 4 + lg;
                int s = __shfl(myid, e);
                float4 v = bf4(hb[(size_t)s * 16 + lq]);
                if (e < take) { acc.x += v.x; acc.y += v.y; acc.z += v.z; acc.w += v.w; }
            }
            j += take;
        }
        acc.x += __shfl_xor(acc.x, 16); acc.y += __shfl_xor(acc.y, 16);
        acc.z += __shfl_xor(acc.z, 16); acc.w += __shfl_xor(acc.w, 16);
        acc.x += __shfl_xor(acc.x, 32); acc.y += __shfl_xor(acc.y, 32);
        acc.z += __shfl_xor(acc.z, 32); acc.w += __shfl_xor(acc.w, 32);
        float a0 = aggE[n * 5 + 0], a1 = aggE[n * 5 + 1], a2 = aggE[n * 5 + 2],
              a3 = aggE[n * 5 + 3], a4 = aggE[n * 5 + 4];
        float c0 = a0 + 8.f;
        float ce = (float)(j1 - j0) + 1.f;
        float4 bb = bf4(hb[(size_t)n * 16 + lq]);
        bb.x = fmaf(c0, ew0.x, bb.x); bb.y = fmaf(c0, ew0.y, bb.y);
        bb.z = fmaf(c0, ew0.z, bb.z); bb.w = fmaf(c0, ew0.w, bb.w);
        bb.x = fmaf(a1, ew1.x, bb.x); bb.y = fmaf(a1, ew1.y, bb.y);
        bb.z = fmaf(a1, ew1.z, bb.z); bb.w = fmaf(a1, ew1.w, bb.w);
        bb.x = fmaf(a2, ew2.x, bb.x); bb.y = fmaf(a2, ew2.y, bb.y);
        bb.z = fmaf(a2, ew2.z, bb.z); bb.w = fmaf(a2, ew2.w, bb.w);
        bb.x = fmaf(a3, ew3.x, bb.x); bb.y = fmaf(a3, ew3.y, bb.y);
        bb.z = fmaf(a3, ew3.z, bb.z); bb.w = fmaf(a3, ew3.w, bb.w);
        bb.x = fmaf(a4, ew4.x, bb.x); bb.y = fmaf(a4, ew4.y, bb.y);
        bb.z = fmaf(a4, ew4.z, bb.z); bb.w = fmaf(a4, ew4.w, bb.w);
        bb.x = fmaf(ce, eb4.x, bb.x); bb.y = fmaf(ce, eb4.y, bb.y);
        bb.z = fmaf(ce, eb4.z, bb.z); bb.w = fmaf(ce, eb4.w, bb.w);
        if (lg == 0) {
            ((float4*)agg)[(size_t)n * 16 + lq] =
                make_float4(acc.x + bb.x, acc.y + bb.y, acc.z + bb.z, acc.w + bb.w);
        }
    }
}

// Fused MLP, row-major LDS tiles (R9 lesson: transposed tiles = 8-way bank
// conflicts on hidT writes, 500K conflict cycles. Row-major k-uniform reads
// are broadcasts; writes spread across banks.)
__global__ __launch_bounds__(256) void k_mlp(const float* __restrict__ agg,
                                             float* __restrict__ h2,
                                             const float* __restrict__ W1l,
                                             const float* __restrict__ b1l,
                                             const float* __restrict__ W2l,
                                             const float* __restrict__ b2l,
                                             float* __restrict__ stats) {
    __shared__ unsigned short w1s[64 * 128];   // [k][j] bf16 16KB
    __shared__ unsigned short w2s[128 * 64];   // [k][f] bf16 16KB
    __shared__ unsigned short as[64 * 68];     // [m][k] bf16 8.7KB
    __shared__ unsigned short hid[64 * 132];   // [m][j] bf16 16.9KB
    __shared__ float b1s[128];
    __shared__ float b2s[64];
    int tid = threadIdx.x;
    int n0 = blockIdx.x * 64;
    // stage weights -> bf16 LDS (tid-linear ushort4 writes: 2-way, free)
    const float4* wg1 = (const float4*)W1l;
    const float4* wg2 = (const float4*)W2l;
    ushort4* w1v = (ushort4*)w1s;
    ushort4* w2v = (ushort4*)w2s;
#pragma unroll
    for (int i = 0; i < 8; ++i) {
        float4 v1 = wg1[tid + i * 256];
        w1v[tid + i * 256] = make_ushort4(f2bf(v1.x), f2bf(v1.y), f2bf(v1.z), f2bf(v1.w));
        float4 v2 = wg2[tid + i * 256];
        w2v[tid + i * 256] = make_ushort4(f2bf(v2.x), f2bf(v2.y), f2bf(v2.z), f2bf(v2.w));
    }
    if (tid < 128) b1s[tid] = b1l[tid];
    if (tid < 64) b2s[tid] = b2l[tid];
    // stage agg tile row-major -> as[m][k] bf16
    const float4* ag4 = (const float4*)agg;
#pragma unroll
    for (int i = 0; i < 4; ++i) {
        int idx = tid + i * 256;  // m=idx>>4, kq=idx&15
        int m = idx >> 4, kq = idx & 15;
        int nn = n0 + m;
        float4 v = make_float4(0.f, 0.f, 0.f, 0.f);
        if (nn < N_NODES) v = ag4[(size_t)nn * 16 + kq];
        *(ushort4*)&as[m * 68 + kq * 4] =
            make_ushort4(f2bf(v.x), f2bf(v.y), f2bf(v.z), f2bf(v.w));
    }
    __syncthreads();
    // phase 1: thread = 8 hid cols (j0) x 4 nodes (m0); reads broadcast over k
    int jg = tid & 15, mg = tid >> 4;
    {
        int j0 = jg * 8;
        int m0 = mg * 4;
        float acc1[4][8] = {};
#pragma unroll 8
        for (int k = 0; k < 64; ++k) {
            float4 wA = bf4(*(const ushort4*)&w1s[k * 128 + j0]);
            float4 wB = bf4(*(const ushort4*)&w1s[k * 128 + j0 + 4]);
            float a0 = bf2f(as[(m0 + 0) * 68 + k]);
            float a1 = bf2f(as[(m0 + 1) * 68 + k]);
            float a2 = bf2f(as[(m0 + 2) * 68 + k]);
            float a3 = bf2f(as[(m0 + 3) * 68 + k]);
            acc1[0][0] = fmaf(a0, wA.x, acc1[0][0]); acc1[0][1] = fmaf(a0, wA.y, acc1[0][1]);
            acc1[0][2] = fmaf(a0, wA.z, acc1[0][2]); acc1[0][3] = fmaf(a0, wA.w, acc1[0][3]);
            acc1[0][4] = fmaf(a0, wB.x, acc1[0][4]); acc1[0][5] = fmaf(a0, wB.y, acc1[0][5]);
            acc1[0][6] = fmaf(a0, wB.z, acc1[0][6]); acc1[0][7] = fmaf(a0, wB.w, acc1[0][7]);
            acc1[1][0] = fmaf(a1, wA.x, acc1[1][0]); acc1[1][1] = fmaf(a1, wA.y, acc1[1][1]);
            acc1[1][2] = fmaf(a1, wA.z, acc1[1][2]); acc1[1][3] = fmaf(a1, wA.w, acc1[1][3]);
            acc1[1][4] = fmaf(a1, wB.x, acc1[1][4]); acc1[1][5] = fmaf(a1, wB.y, acc1[1][5]);
            acc1[1][6] = fmaf(a1, wB.z, acc1[1][6]); acc1[1][7] = fmaf(a1, wB.w, acc1[1][7]);
            acc1[2][0] = fmaf(a2, wA.x, acc1[2][0]); acc1[2][1] = fmaf(a2, wA.y, acc1[2][1]);
            acc1[2][2] = fmaf(a2, wA.z, acc1[2][2]); acc1[2][3] = fmaf(a2, wA.w, acc1[2][3]);
            acc1[2][4] = fmaf(a2, wB.x, acc1[2][4]); acc1[2][5] = fmaf(a2, wB.y, acc1[2][5]);
            acc1[2][6] = fmaf(a2, wB.z, acc1[2][6]); acc1[2][7] = fmaf(a2, wB.w, acc1[2][7]);
            acc1[3][0] = fmaf(a3, wA.x, acc1[3][0]); acc1[3][1] = fmaf(a3, wA.y, acc1[3][1]);
            acc1[3][2] = fmaf(a3, wA.z, acc1[3][2]); acc1[3][3] = fmaf(a3, wA.w, acc1[3][3]);
            acc1[3][4] = fmaf(a3, wB.x, acc1[3][4]); acc1[3][5] = fmaf(a3, wB.y, acc1[3][5]);
            acc1[3][6] = fmaf(a3, wB.z, acc1[3][6]); acc1[3][7] = fmaf(a3, wB.w, acc1[3][7]);
        }
#pragma unroll
        for (int i = 0; i < 4; ++i) {
            int m = m0 + i;
            ushort4 oA, oB;
            oA.x = f2bf(fmaxf(acc1[i][0] + b1s[j0 + 0], 0.f));
            oA.y = f2bf(fmaxf(acc1[i][1] + b1s[j0 + 1], 0.f));
            oA.z = f2bf(fmaxf(acc1[i][2] + b1s[j0 + 2], 0.f));
            oA.w = f2bf(fmaxf(acc1[i][3] + b1s[j0 + 3], 0.f));
            oB.x = f2bf(fmaxf(acc1[i][4] + b1s[j0 + 4], 0.f));
            oB.y = f2bf(fmaxf(acc1[i][5] + b1s[j0 + 5], 0.f));
            oB.z = f2bf(fmaxf(acc1[i][6] + b1s[j0 + 6], 0.f));
            oB.w = f2bf(fmaxf(acc1[i][7] + b1s[j0 + 7], 0.f));
            *(ushort4*)&hid[m * 132 + j0] = oA;
            *(ushort4*)&hid[m * 132 + j0 + 4] = oB;
        }
    }
    __syncthreads();
    // phase 2: thread = 4 out cols (f0) x 4 nodes (same m0); broadcast reads
    int f0 = jg * 4;
    int m0 = mg * 4;
    float acc2[4][4] = {};
#pragma unroll 8
    for (int k = 0; k < 128; ++k) {
        float4 w = bf4(((const ushort4*)w2s)[k * 16 + jg]);
        float a0 = bf2f(hid[(m0 + 0) * 132 + k]);
        float a1 = bf2f(hid[(m0 + 1) * 132 + k]);
        float a2 = bf2f(hid[(m0 + 2) * 132 + k]);
        float a3 = bf2f(hid[(m0 + 3) * 132 + k]);
        acc2[0][0] = fmaf(a0, w.x, acc2[0][0]); acc2[0][1] = fmaf(a0, w.y, acc2[0][1]);
        acc2[0][2] = fmaf(a0, w.z, acc2[0][2]); acc2[0][3] = fmaf(a0, w.w, acc2[0][3]);
        acc2[1][0] = fmaf(a1, w.x, acc2[1][0]); acc2[1][1] = fmaf(a1, w.y, acc2[1][1]);
        acc2[1][2] = fmaf(a1, w.z, acc2[1][2]); acc2[1][3] = fmaf(a1, w.w, acc2[1][3]);
        acc2[2][0] = fmaf(a2, w.x, acc2[2][0]); acc2[2][1] = fmaf(a2, w.y, acc2[2][1]);
        acc2[2][2] = fmaf(a2, w.z, acc2[2][2]); acc2[2][3] = fmaf(a2, w.w, acc2[2][3]);
        acc2[3][0] = fmaf(a3, w.x, acc2[3][0]); acc2[3][1] = fmaf(a3, w.y, acc2[3][1]);
        acc2[3][2] = fmaf(a3, w.z, acc2[3][2]); acc2[3][3] = fmaf(a3, w.w, acc2[3][3]);
    }
    float sf[4] = {0.f, 0.f, 0.f, 0.f}, qf[4] = {0.f, 0.f, 0.f, 0.f};
#pragma unroll
    for (int i = 0; i < 4; ++i) {
        int nn = n0 + m0 + i;
        if (nn < N_NODES) {
            float v0 = acc2[i][0] + b2s[f0 + 0];
            float v1 = acc2[i][1] + b2s[f0 + 1];
            float v2 = acc2[i][2] + b2s[f0 + 2];
            float v3 = acc2[i][3] + b2s[f0 + 3];
            *(float4*)&h2[(size_t)nn * EMB + f0] = make_float4(v0, v1, v2, v3);
            sf[0] += v0; sf[1] += v1; sf[2] += v2; sf[3] += v3;
            qf[0] = fmaf(v0, v0, qf[0]); qf[1] = fmaf(v1, v1, qf[1]);
            qf[2] = fmaf(v2, v2, qf[2]); qf[3] = fmaf(v3, v3, qf[3]);
        }
    }
    __syncthreads();  // done with hid; reuse as reduction scratch (needs 8KB)
    float* red = (float*)hid;
#pragma unroll
    for (int j = 0; j < 4; ++j) {
        red[mg * 64 + f0 + j] = sf[j];
        red[1024 + mg * 64 + f0 + j] = qf[j];
    }
    __syncthreads();
    if (tid < 64) {
        float s = 0.f, q = 0.f;
#pragma unroll
        for (int m = 0; m < 16; ++m) {
            s += red[m * 64 + tid];
            q += red[1024 + m * 64 + tid];
        }
        atomAddF(&stats[tid], s);
        atomAddF(&stats[64 + tid], q);
    }
}

// BN apply + ELU (layers 0,1): h(bf16) = elu(bn(h2))
__global__ void k_bn(const float* __restrict__ h2, unsigned short* __restrict__ h,
                     const float* __restrict__ stats, const float* __restrict__ gam,
                     const float* __restrict__ bet) {
    int gid = blockIdx.x * 256 + threadIdx.x;
    if (gid >= N_NODES * EMB) return;
    int f = gid & 63;
    const float invN = 1.f / (float)N_NODES;
    float mean = stats[f] * invN;
    float var = stats[64 + f] * invN - mean * mean;
    float inv = rsqrtf(var + BN_EPS);
    float v = (h2[gid] - mean) * inv * gam[f] + bet[f];
    h[gid] = f2bf(v > 0.f ? v : expm1f(v));
}

// last layer: BN only for the 250 super-nodes (h2 stays fp32)
__global__ void k_bnout(const float* __restrict__ h2, const int* __restrict__ last,
                        const float* __restrict__ stats, const float* __restrict__ gam,
                        const float* __restrict__ bet, float* __restrict__ out) {
    int gid = blockIdx.x * 256 + threadIdx.x;
    if (gid >= NGRAPH * EMB) return;
    int b = gid >> 6, f = gid & 63;
    const float invN = 1.f / (float)N_NODES;
    float mean = stats[f] * invN;
    float var = stats[64 + f] * invN - mean * mean;
    float inv = rsqrtf(var + BN_EPS);
    out[gid] = (h2[last[b] * EMB + f] - mean) * inv * gam[f] + bet[f];
}

extern "C" void kernel_launch(void* const* d_in, const int* in_sizes, int n_in,
                              void* d_out, int out_size, void* d_ws, size_t ws_size,
                              hipStream_t stream) {
    const float* x   = (const float*)d_in[0];
    const float* ea  = (const float*)d_in[1];
    const int*   eidx= (const int*)d_in[2];
    const int*   last= (const int*)d_in[3];
    const float* xW  = (const float*)d_in[4];
    const float* xb  = (const float*)d_in[5];
    const float* eW  = (const float*)d_in[6];
    const float* eb  = (const float*)d_in[7];
    const float* W1  = (const float*)d_in[8];
    const float* b1  = (const float*)d_in[9];
    const float* W2  = (const float*)d_in[10];
    const float* b2  = (const float*)d_in[11];
    const float* gam = (const float*)d_in[12];
    const float* bet = (const float*)d_in[13];
    float* out = (float*)d_out;

    const int* srcI = eidx;
    const int* dstI = eidx + N_EDGES;

    float* hslot  = (float*)d_ws;              // h bf16 uses half this slot
    float* agg    = hslot + N_NODES * EMB;     // N*64 f32 (h2 in loop)
    float* hidslot= agg + N_NODES * EMB;       // scratch (csrE alias)
    float* aggE   = hidslot + N_NODES * HID;
    float* stats  = aggE + NBKT * BKT_SZ * EFD;
    int* rowstart = (int*)(stats + NLAYER * 2 * EMB);
    int* csr      = rowstart + N_NODES + 1;
    int* cntmat   = csr + N_EDGES;
    int* off2     = cntmat + CNTM;
    int* bsum     = off2 + CNTM;
    int* boff     = bsum + NB2;
    unsigned short* h = (unsigned short*)hslot;
    int2* bufSD   = (int2*)agg;                // alias, dead before loop
    int*  csrE    = (int*)hidslot;             // alias, dead after aggE

    hipMemsetAsync(stats, 0, NLAYER * 2 * EMB * sizeof(float), stream);

    k_input<<<(N_NODES * EMB + 255) / 256, 256, 0, stream>>>(x, xW, xb, h);
    k_binA<<<NCHK, 256, 0, stream>>>(dstI, cntmat);
    k_gscanA<<<NB2, 256, 0, stream>>>(cntmat, CNTM, bsum);
    k_gscanB<<<1, 256, 0, stream>>>(bsum, NB2, boff);
    k_gscanC<<<NB2, 256, 0, stream>>>(cntmat, CNTM, boff, off2);
    k_binC<<<NCHK, 256, 0, stream>>>(srcI, dstI, off2, bufSD);
    k_binD<<<NBKT, 256, 0, stream>>>(bufSD, off2, csr, csrE, rowstart);
    k_aggE<<<(N_NODES * 64 + 255) / 256, 256, 0, stream>>>(rowstart, csrE, ea, aggE);

    const int aggBlocks = ((N_NODES + 3) / 4 * 64 + 255) / 256;  // 4 nodes/wave
    const int mlpBlocks = (N_NODES + 63) / 64;
    for (int l = 0; l < NLAYER; ++l) {
        k_agg<<<aggBlocks, 256, 0, stream>>>(
            h, agg, rowstart, csr, aggE, eW + l * EFD * EMB, eb + l * EMB);
        k_mlp<<<mlpBlocks, 256, 0, stream>>>(agg, agg, W1 + l * EMB * HID, b1 + l * HID,
                                             W2 + l * HID * EMB, b2 + l * EMB,
                                             stats + l * 2 * EMB);
        if (l < NLAYER - 1) {
            k_bn<<<(N_NODES * EMB + 255) / 256, 256, 0, stream>>>(
                agg, h, stats + l * 2 * EMB, gam + l * EMB, bet + l * EMB);
        } else {
            k_bnout<<<(NGRAPH * EMB + 255) / 256, 256, 0, stream>>>(
                agg, last, stats + l * 2 * EMB, gam + l * EMB, bet + l * EMB, out);
        }
    }
}

// Round 11
// 346.660 us; speedup vs baseline: 1.3053x; 1.1342x over previous
//
#include <hip/hip_runtime.h>

#define N_NODES 50000
#define N_EDGES 1000000
#define EMB     64
#define HID     128
#define NLAYER  3
#define NGRAPH  250
#define XFD     7
#define EFD     5
#define BN_EPS  1e-5f

// two-level counting sort geometry
#define BKT_SH 8
#define BKT_SZ 256
#define NBKT   ((N_NODES + BKT_SZ - 1) / BKT_SZ)  // 196
#define CHKE   4096
#define NCHK   ((N_EDGES + CHKE - 1) / CHKE)      // 245
#define CNTM   (NBKT * NCHK)                      // 48020
#define NB2    ((CNTM + 255) / 256)               // 188

typedef short bf8_t __attribute__((ext_vector_type(8)));   // 8 bf16 (4 VGPRs)
typedef float f4_t  __attribute__((ext_vector_type(4)));   // MFMA acc

union FragU {
    uint4 q;
    bf8_t v;
    unsigned short u[8];
};

__device__ __forceinline__ void atomAddF(float* p, float v) {
    __hip_atomic_fetch_add(p, v, __ATOMIC_RELAXED, __HIP_MEMORY_SCOPE_AGENT);
}

__device__ __forceinline__ unsigned short f2bf(float f) {
    unsigned int u = __float_as_uint(f);
    u += 0x7fffu + ((u >> 16) & 1u);
    return (unsigned short)(u >> 16);
}
__device__ __forceinline__ float bf2f(unsigned short s) {
    return __uint_as_float(((unsigned int)s) << 16);
}
__device__ __forceinline__ float4 bf4(ushort4 u) {
    return make_float4(bf2f(u.x), bf2f(u.y), bf2f(u.z), bf2f(u.w));
}

// h(bf16) = x @ xW + xb
__global__ void k_input(const float* __restrict__ x, const float* __restrict__ xW,
                        const float* __restrict__ xb, unsigned short* __restrict__ h) {
    int gid = blockIdx.x * 256 + threadIdx.x;
    if (gid >= N_NODES * EMB) return;
    int n = gid >> 6, f = gid & 63;
    float acc = xb[f];
#pragma unroll
    for (int k = 0; k < XFD; ++k) acc = fmaf(x[n * XFD + k], xW[k * EMB + f], acc);
    h[gid] = f2bf(acc);
}

// Pack W1/W2 into MFMA B-fragment order (one-time):
// B-frag lane layout: B[k = 32*s + 8*(lane>>4) + j][n = 16*t + (lane&15)]
// pw[((ts*64 + lane)*8 + j] ; W1: ts=t*2+s (t<8,s<2) ; W2: ts=t*4+s (t<4,s<4)
__global__ void k_packW(const float* __restrict__ W1, const float* __restrict__ W2,
                        unsigned short* __restrict__ pw1, unsigned short* __restrict__ pw2) {
    int gid = blockIdx.x * 256 + threadIdx.x;         // 3*16384 total
    int layer = gid >> 14;
    int r = gid & 16383;
    if (layer >= NLAYER) return;
    if (r < 8192) {
        int p = r;
        int j = p & 7, lane = (p >> 3) & 63, ts = p >> 9;  // ts<16
        int t = ts >> 1, s = ts & 1;
        int k = 32 * s + 8 * (lane >> 4) + j;
        int n = 16 * t + (lane & 15);
        pw1[layer * 8192 + p] = f2bf(W1[layer * EMB * HID + k * HID + n]);
    } else {
        int p = r - 8192;
        int j = p & 7, lane = (p >> 3) & 63, ts = p >> 9;  // ts<16
        int t = ts >> 2, s = ts & 3;
        int k = 32 * s + 8 * (lane >> 4) + j;
        int n = 16 * t + (lane & 15);
        pw2[layer * 8192 + p] = f2bf(W2[layer * HID * EMB + k * EMB + n]);
    }
}

// ---- phase A: per-chunk coarse-bucket histogram ----
__global__ __launch_bounds__(256) void k_binA(const int* __restrict__ dst,
                                              int* __restrict__ cntmat) {
    __shared__ int hist[NBKT];
    int tid = threadIdx.x, c = blockIdx.x;
    for (int i = tid; i < NBKT; i += 256) hist[i] = 0;
    __syncthreads();
    int e0 = c * CHKE, e1 = min(e0 + CHKE, N_EDGES);
    for (int i = e0 + tid; i < e1; i += 256) atomicAdd(&hist[dst[i] >> BKT_SH], 1);
    __syncthreads();
    for (int b = tid; b < NBKT; b += 256) cntmat[b * NCHK + c] = hist[b];
}

// ---- 3-phase multi-block exclusive scan ----
__global__ __launch_bounds__(256) void k_gscanA(const int* __restrict__ in, int n,
                                                int* __restrict__ bsum) {
    int tid = threadIdx.x, lane = tid & 63, wid = tid >> 6;
    int i = blockIdx.x * 256 + tid;
    int v = (i < n) ? in[i] : 0;
#pragma unroll
    for (int off = 32; off; off >>= 1) v += __shfl_down(v, off);
    __shared__ int ws[4];
    if (lane == 0) ws[wid] = v;
    __syncthreads();
    if (tid == 0) bsum[blockIdx.x] = ws[0] + ws[1] + ws[2] + ws[3];
}

__global__ __launch_bounds__(256) void k_gscanB(const int* __restrict__ bsum, int nb,
                                                int* __restrict__ boff) {
    int tid = threadIdx.x, lane = tid & 63, wid = tid >> 6;
    int v = (tid < nb) ? bsum[tid] : 0;
    int x = v;
#pragma unroll
    for (int off = 1; off < 64; off <<= 1) {
        int y = __shfl_up(x, off);
        if (lane >= off) x += y;
    }
    __shared__ int wtot[4];
    if (lane == 63) wtot[wid] = x;
    __syncthreads();
    int woff = 0;
    for (int w = 0; w < wid; ++w) woff += wtot[w];
    if (tid < nb) boff[tid] = woff + x - v;
}

__global__ __launch_bounds__(256) void k_gscanC(const int* __restrict__ in, int n,
                                                const int* __restrict__ boff,
                                                int* __restrict__ out) {
    int tid = threadIdx.x, lane = tid & 63, wid = tid >> 6;
    int i = blockIdx.x * 256 + tid;
    int v = (i < n) ? in[i] : 0;
    int x = v;
#pragma unroll
    for (int off = 1; off < 64; off <<= 1) {
        int y = __shfl_up(x, off);
        if (lane >= off) x += y;
    }
    __shared__ int wtot[4];
    if (lane == 63) wtot[wid] = x;
    __syncthreads();
    int woff = boff[blockIdx.x];
    for (int w = 0; w < wid; ++w) woff += wtot[w];
    if (i < n) out[i] = woff + x - v;
}

// ---- phase C: coarse scatter of packed {src, d_local<<20|eid} ----
__global__ __launch_bounds__(256) void k_binC(const int* __restrict__ src,
                                              const int* __restrict__ dst,
                                              const int* __restrict__ off2,
                                              int2* __restrict__ bufSD) {
    __shared__ int cur[NBKT];
    int tid = threadIdx.x, c = blockIdx.x;
    for (int b = tid; b < NBKT; b += 256) cur[b] = off2[b * NCHK + c];
    __syncthreads();
    int e0 = c * CHKE, e1 = min(e0 + CHKE, N_EDGES);
    for (int i = e0 + tid; i < e1; i += 256) {
        int d = dst[i];
        int b = d >> BKT_SH;
        int p = atomicAdd(&cur[b], 1);
        bufSD[p] = make_int2(src[i], ((d & (BKT_SZ - 1)) << 20) | i);
    }
}

// ---- phase D: per-bucket fine sort -> csr + csrE + rowstart ----
__global__ __launch_bounds__(256) void k_binD(const int2* __restrict__ bufSD,
                                              const int* __restrict__ off2,
                                              int* __restrict__ csr,
                                              int* __restrict__ csrE,
                                              int* __restrict__ rowstart) {
    __shared__ int hist[BKT_SZ];
    __shared__ int cur[BKT_SZ];
    __shared__ int wtot[4];
    int tid = threadIdx.x, b = blockIdx.x;
    int bstart = off2[b * NCHK];
    int bend = (b + 1 < NBKT) ? off2[(b + 1) * NCHK] : N_EDGES;
    hist[tid] = 0;
    __syncthreads();
    for (int j = bstart + tid; j < bend; j += 256)
        atomicAdd(&hist[bufSD[j].y >> 20], 1);
    __syncthreads();
    int lane = tid & 63, wid = tid >> 6;
    int v = hist[tid], x = v;
#pragma unroll
    for (int off = 1; off < 64; off <<= 1) {
        int y = __shfl_up(x, off);
        if (lane >= off) x += y;
    }
    if (lane == 63) wtot[wid] = x;
    __syncthreads();
    int woff = 0;
    for (int w = 0; w < wid; ++w) woff += wtot[w];
    int ex = woff + x - v;
    cur[tid] = ex;
    int node = b * BKT_SZ + tid;
    if (node < N_NODES) rowstart[node] = bstart + ex;
    if (b == NBKT - 1 && tid == 0) rowstart[N_NODES] = N_EDGES;
    __syncthreads();
    for (int j = bstart + tid; j < bend; j += 256) {
        int2 t = bufSD[j];
        int local = t.y >> 20;
        int p = atomicAdd(&cur[local], 1);
        csr[bstart + p] = t.x;
        csrE[bstart + p] = t.y & 0xFFFFF;
    }
}

// aggE[n] = sum of ea over in-edges (wave/node, full-device concurrency)
__global__ __launch_bounds__(256) void k_aggE(const int* __restrict__ rowstart,
                                              const int* __restrict__ csrE,
                                              const float* __restrict__ ea,
                                              float* __restrict__ aggE) {
    int wid = (blockIdx.x * 256 + threadIdx.x) >> 6;
    int lane = threadIdx.x & 63;
    if (wid >= N_NODES) return;
    int j0 = rowstart[wid], j1 = rowstart[wid + 1];
    float s0 = 0.f, s1 = 0.f, s2 = 0.f, s3 = 0.f, s4 = 0.f;
    for (int j = j0 + lane; j < j1; j += 64) {
        int e = csrE[j];
        const float* p = ea + (size_t)e * EFD;
        s0 += p[0]; s1 += p[1]; s2 += p[2]; s3 += p[3]; s4 += p[4];
    }
#pragma unroll
    for (int off = 32; off; off >>= 1) {
        s0 += __shfl_down(s0, off);
        s1 += __shfl_down(s1, off);
        s2 += __shfl_down(s2, off);
        s3 += __shfl_down(s3, off);
        s4 += __shfl_down(s4, off);
    }
    if (lane == 0) {
        float* o = aggE + (size_t)wid * EFD;
        o[0] = s0; o[1] = s1; o[2] = s2; o[3] = s3; o[4] = s4;
    }
}

// agg(f32): wave handles 4 consecutive nodes
__global__ __launch_bounds__(256) void k_agg(const unsigned short* __restrict__ h,
                                             float* __restrict__ agg,
                                             const int* __restrict__ rowstart,
                                             const int* __restrict__ csr,
                                             const float* __restrict__ aggE,
                                             const float* __restrict__ eWl,
                                             const float* __restrict__ ebl) {
    int wave = (blockIdx.x * 256 + threadIdx.x) >> 6;
    int lane = threadIdx.x & 63;
    int nbase = wave * 4;
    if (nbase >= N_NODES) return;
    int lg = lane >> 4, lq = lane & 15;
    const ushort4* hb = (const ushort4*)h;
    const float4* eW4 = (const float4*)eWl;
    float4 ew0 = eW4[lq], ew1 = eW4[16 + lq], ew2 = eW4[32 + lq],
           ew3 = eW4[48 + lq], ew4 = eW4[64 + lq];
    float4 eb4 = ((const float4*)ebl)[lq];
    int nend = min(nbase + 4, N_NODES);
    for (int n = nbase; n < nend; ++n) {
        int j0 = rowstart[n], j1 = rowstart[n + 1];
        float4 acc = make_float4(0.f, 0.f, 0.f, 0.f);
        int j = j0;
        while (j < j1) {
            int take = j1 - j;
            if (take > 64) take = 64;
            int myid = (lane < take) ? csr[j + lane] : 0;
            int nt = (take + 3) >> 2;
            int t = 0;
            for (; t + 4 <= nt; t += 4) {
                int e0 = t * 4 + lg, e1 = e0 + 4, e2 = e0 + 8, e3 = e0 + 12;
                int s0 = __shfl(myid, e0), s1 = __shfl(myid, e1),
                    s2 = __shfl(myid, e2), s3 = __shfl(myid, e3);
                float4 v0 = bf4(hb[(size_t)s0 * 16 + lq]);
                float4 v1 = bf4(hb[(size_t)s1 * 16 + lq]);
                float4 v2 = bf4(hb[(size_t)s2 * 16 + lq]);
                float4 v3 = bf4(hb[(size_t)s3 * 16 + lq]);
                if (e0 < take) { acc.x += v0.x; acc.y += v0.y; acc.z += v0.z; acc.w += v0.w; }
                if (e1 < take) { acc.x += v1.x; acc.y += v1.y; acc.z += v1.z; acc.w += v1.w; }
                if (e2 < take) { acc.x += v2.x; acc.y += v2.y; acc.z += v2.z; acc.w += v2.w; }
                if (e3 < take) { acc.x += v3.x; acc.y += v3.y; acc.z += v3.z; acc.w += v3.w; }
            }
            for (; t < nt; ++t) {
                int e = t * 4 + lg;
                int s = __shfl(myid, e);
                float4 v = bf4(hb[(size_t)s * 16 + lq]);
                if (e < take) { acc.x += v.x; acc.y += v.y; acc.z += v.z; acc.w += v.w; }
            }
            j += take;
        }
        acc.x += __shfl_xor(acc.x, 16); acc.y += __shfl_xor(acc.y, 16);
        acc.z += __shfl_xor(acc.z, 16); acc.w += __shfl_xor(acc.w, 16);
        acc.x += __shfl_xor(acc.x, 32); acc.y += __shfl_xor(acc.y, 32);
        acc.z += __shfl_xor(acc.z, 32); acc.w += __shfl_xor(acc.w, 32);
        float a0 = aggE[n * 5 + 0], a1 = aggE[n * 5 + 1], a2 = aggE[n * 5 + 2],
              a3 = aggE[n * 5 + 3], a4 = aggE[n * 5 + 4];
        float c0 = a0 + 8.f;
        float ce = (float)(j1 - j0) + 1.f;
        float4 bb = bf4(hb[(size_t)n * 16 + lq]);
        bb.x = fmaf(c0, ew0.x, bb.x); bb.y = fmaf(c0, ew0.y, bb.y);
        bb.z = fmaf(c0, ew0.z, bb.z); bb.w = fmaf(c0, ew0.w, bb.w);
        bb.x = fmaf(a1, ew1.x, bb.x); bb.y = fmaf(a1, ew1.y, bb.y);
        bb.z = fmaf(a1, ew1.z, bb.z); bb.w = fmaf(a1, ew1.w, bb.w);
        bb.x = fmaf(a2, ew2.x, bb.x); bb.y = fmaf(a2, ew2.y, bb.y);
        bb.z = fmaf(a2, ew2.z, bb.z); bb.w = fmaf(a2, ew2.w, bb.w);
        bb.x = fmaf(a3, ew3.x, bb.x); bb.y = fmaf(a3, ew3.y, bb.y);
        bb.z = fmaf(a3, ew3.z, bb.z); bb.w = fmaf(a3, ew3.w, bb.w);
        bb.x = fmaf(a4, ew4.x, bb.x); bb.y = fmaf(a4, ew4.y, bb.y);
        bb.z = fmaf(a4, ew4.z, bb.z); bb.w = fmaf(a4, ew4.w, bb.w);
        bb.x = fmaf(ce, eb4.x, bb.x); bb.y = fmaf(ce, eb4.y, bb.y);
        bb.z = fmaf(ce, eb4.z, bb.z); bb.w = fmaf(ce, eb4.w, bb.w);
        if (lg == 0) {
            ((float4*)agg)[(size_t)n * 16 + lq] =
                make_float4(acc.x + bb.x, acc.y + bb.y, acc.z + bb.z, acc.w + bb.w);
        }
    }
}

// Fused MLP via MFMA (R10 lesson: VALU GEMM was issue-bound at 34% VALUBusy,
// MfmaUtil 0 — conflicts were NOT the limiter). 64-node tile, 4 waves; each
// wave owns 16 rows. hidden round-trips LDS (wave-local) for C->A relayout.
// Weights pre-packed in B-frag order -> one dwordx4/frag, no weight LDS.
__global__ __launch_bounds__(256) void k_mlp(const float* __restrict__ agg,
                                             float* __restrict__ h2,
                                             const unsigned short* __restrict__ pw1,
                                             const float* __restrict__ b1l,
                                             const unsigned short* __restrict__ pw2,
                                             const float* __restrict__ b2l,
                                             float* __restrict__ stats) {
    __shared__ __align__(16) unsigned short hid[64 * 136];  // [m][j], 17.4KB
    int tid = threadIdx.x;
    int w = tid >> 6, lane = tid & 63;
    int q = lane >> 4, l15 = lane & 15;
    int n0 = blockIdx.x * 64;
    // ---- phase 1: hidden = relu(agg @ W1 + b1), MFMA ----
    // A-frag: A[m=l15][k=32s+8q+j] from agg row (n0+16w+l15)
    int mrow = n0 + 16 * w + l15;
    const float* arow = agg + (size_t)(mrow < N_NODES ? mrow : N_NODES - 1) * EMB;
    FragU fa[2];
#pragma unroll
    for (int s = 0; s < 2; ++s) {
        float4 x0 = *(const float4*)&arow[32 * s + 8 * q];
        float4 x1 = *(const float4*)&arow[32 * s + 8 * q + 4];
        fa[s].u[0] = f2bf(x0.x); fa[s].u[1] = f2bf(x0.y);
        fa[s].u[2] = f2bf(x0.z); fa[s].u[3] = f2bf(x0.w);
        fa[s].u[4] = f2bf(x1.x); fa[s].u[5] = f2bf(x1.y);
        fa[s].u[6] = f2bf(x1.z); fa[s].u[7] = f2bf(x1.w);
    }
    const uint4* w1f = (const uint4*)pw1;
    f4_t acc1[8];
#pragma unroll
    for (int t = 0; t < 8; ++t) {
        acc1[t] = (f4_t){0.f, 0.f, 0.f, 0.f};
        FragU b0, b1;
        b0.q = w1f[(t * 2 + 0) * 64 + lane];
        b1.q = w1f[(t * 2 + 1) * 64 + lane];
        acc1[t] = __builtin_amdgcn_mfma_f32_16x16x32_bf16(fa[0].v, b0.v, acc1[t], 0, 0, 0);
        acc1[t] = __builtin_amdgcn_mfma_f32_16x16x32_bf16(fa[1].v, b1.v, acc1[t], 0, 0, 0);
    }
    // bias+relu, C layout (row=q*4+r, col=16t+l15) -> hid[m][col] bf16
#pragma unroll
    for (int t = 0; t < 8; ++t) {
        int col = 16 * t + l15;
        float bv = b1l[col];
#pragma unroll
        for (int r = 0; r < 4; ++r) {
            int m = 16 * w + q * 4 + r;
            hid[m * 136 + col] = f2bf(fmaxf(acc1[t][r] + bv, 0.f));
        }
    }
    // ---- phase 2: h2 = hidden @ W2 + b2 (wave-local hid, no barrier needed) ----
    FragU fa2[4];
#pragma unroll
    for (int s = 0; s < 4; ++s)
        fa2[s].q = *(const uint4*)&hid[(16 * w + l15) * 136 + 32 * s + 8 * q];
    const uint4* w2f = (const uint4*)pw2;
    f4_t acc2[4];
#pragma unroll
    for (int t = 0; t < 4; ++t) {
        acc2[t] = (f4_t){0.f, 0.f, 0.f, 0.f};
#pragma unroll
        for (int s = 0; s < 4; ++s) {
            FragU b;
            b.q = w2f[(t * 4 + s) * 64 + lane];
            acc2[t] = __builtin_amdgcn_mfma_f32_16x16x32_bf16(fa2[s].v, b.v, acc2[t], 0, 0, 0);
        }
    }
    float sacc[4] = {0.f, 0.f, 0.f, 0.f}, qacc[4] = {0.f, 0.f, 0.f, 0.f};
#pragma unroll
    for (int t = 0; t < 4; ++t) {
        int col = 16 * t + l15;
        float bv = b2l[col];
#pragma unroll
        for (int r = 0; r < 4; ++r) {
            int nn = n0 + 16 * w + q * 4 + r;
            if (nn < N_NODES) {
                float v = acc2[t][r] + bv;
                h2[(size_t)nn * EMB + col] = v;
                sacc[t] += v;
                qacc[t] = fmaf(v, v, qacc[t]);
            }
        }
    }
    // stats: features col=16t+l15; reduce across quads then across waves
#pragma unroll
    for (int t = 0; t < 4; ++t) {
        sacc[t] += __shfl_xor(sacc[t], 16); qacc[t] += __shfl_xor(qacc[t], 16);
        sacc[t] += __shfl_xor(sacc[t], 32); qacc[t] += __shfl_xor(qacc[t], 32);
    }
    __syncthreads();  // all waves done with hid; reuse as float scratch (2KB)
    float* red = (float*)hid;
    if (q == 0) {
#pragma unroll
        for (int t = 0; t < 4; ++t) {
            red[w * 64 + 16 * t + l15] = sacc[t];
            red[256 + w * 64 + 16 * t + l15] = qacc[t];
        }
    }
    __syncthreads();
    if (tid < 64) {
        float s = red[tid] + red[64 + tid] + red[128 + tid] + red[192 + tid];
        float qq = red[256 + tid] + red[320 + tid] + red[384 + tid] + red[448 + tid];
        atomAddF(&stats[tid], s);
        atomAddF(&stats[64 + tid], qq);
    }
}

// BN apply + ELU (layers 0,1): h(bf16) = elu(bn(h2))
__global__ void k_bn(const float* __restrict__ h2, unsigned short* __restrict__ h,
                     const float* __restrict__ stats, const float* __restrict__ gam,
                     const float* __restrict__ bet) {
    int gid = blockIdx.x * 256 + threadIdx.x;
    if (gid >= N_NODES * EMB) return;
    int f = gid & 63;
    const float invN = 1.f / (float)N_NODES;
    float mean = stats[f] * invN;
    float var = stats[64 + f] * invN - mean * mean;
    float inv = rsqrtf(var + BN_EPS);
    float v = (h2[gid] - mean) * inv * gam[f] + bet[f];
    h[gid] = f2bf(v > 0.f ? v : expm1f(v));
}

// last layer: BN only for the 250 super-nodes (h2 stays fp32)
__global__ void k_bnout(const float* __restrict__ h2, const int* __restrict__ last,
                        const float* __restrict__ stats, const float* __restrict__ gam,
                        const float* __restrict__ bet, float* __restrict__ out) {
    int gid = blockIdx.x * 256 + threadIdx.x;
    if (gid >= NGRAPH * EMB) return;
    int b = gid >> 6, f = gid & 63;
    const float invN = 1.f / (float)N_NODES;
    float mean = stats[f] * invN;
    float var = stats[64 + f] * invN - mean * mean;
    float inv = rsqrtf(var + BN_EPS);
    out[gid] = (h2[last[b] * EMB + f] - mean) * inv * gam[f] + bet[f];
}

extern "C" void kernel_launch(void* const* d_in, const int* in_sizes, int n_in,
                              void* d_out, int out_size, void* d_ws, size_t ws_size,
                              hipStream_t stream) {
    const float* x   = (const float*)d_in[0];
    const float* ea  = (const float*)d_in[1];
    const int*   eidx= (const int*)d_in[2];
    const int*   last= (const int*)d_in[3];
    const float* xW  = (const float*)d_in[4];
    const float* xb  = (const float*)d_in[5];
    const float* eW  = (const float*)d_in[6];
    const float* eb  = (const float*)d_in[7];
    const float* W1  = (const float*)d_in[8];
    const float* b1  = (const float*)d_in[9];
    const float* W2  = (const float*)d_in[10];
    const float* b2  = (const float*)d_in[11];
    const float* gam = (const float*)d_in[12];
    const float* bet = (const float*)d_in[13];
    float* out = (float*)d_out;

    const int* srcI = eidx;
    const int* dstI = eidx + N_EDGES;

    float* hslot  = (float*)d_ws;              // h bf16 uses half this slot
    float* agg    = hslot + N_NODES * EMB;     // N*64 f32 (h2 in loop)
    float* hidslot= agg + N_NODES * EMB;       // scratch (csrE alias)
    float* aggE   = hidslot + N_NODES * HID;
    float* stats  = aggE + NBKT * BKT_SZ * EFD;
    int* rowstart = (int*)(stats + NLAYER * 2 * EMB);
    int* csr      = rowstart + N_NODES + 1;
    int* cntmat   = csr + N_EDGES;
    int* off2     = cntmat + CNTM;
    int* bsum     = off2 + CNTM;
    int* boff     = bsum + NB2;
    unsigned short* pw1 = (unsigned short*)(boff + NB2);   // 3*8192 bf16
    unsigned short* pw2 = pw1 + NLAYER * EMB * HID;        // 3*8192 bf16
    unsigned short* h = (unsigned short*)hslot;
    int2* bufSD   = (int2*)agg;                // alias, dead before loop
    int*  csrE    = (int*)hidslot;             // alias, dead after aggE

    hipMemsetAsync(stats, 0, NLAYER * 2 * EMB * sizeof(float), stream);

    k_input<<<(N_NODES * EMB + 255) / 256, 256, 0, stream>>>(x, xW, xb, h);
    k_packW<<<(NLAYER * 2 * EMB * HID + 255) / 256, 256, 0, stream>>>(W1, W2, pw1, pw2);
    k_binA<<<NCHK, 256, 0, stream>>>(dstI, cntmat);
    k_gscanA<<<NB2, 256, 0, stream>>>(cntmat, CNTM, bsum);
    k_gscanB<<<1, 256, 0, stream>>>(bsum, NB2, boff);
    k_gscanC<<<NB2, 256, 0, stream>>>(cntmat, CNTM, boff, off2);
    k_binC<<<NCHK, 256, 0, stream>>>(srcI, dstI, off2, bufSD);
    k_binD<<<NBKT, 256, 0, stream>>>(bufSD, off2, csr, csrE, rowstart);
    k_aggE<<<(N_NODES * 64 + 255) / 256, 256, 0, stream>>>(rowstart, csrE, ea, aggE);

    const int aggBlocks = ((N_NODES + 3) / 4 * 64 + 255) / 256;  // 4 nodes/wave
    const int mlpBlocks = (N_NODES + 63) / 64;                   // 782
    for (int l = 0; l < NLAYER; ++l) {
        k_agg<<<aggBlocks, 256, 0, stream>>>(
            h, agg, rowstart, csr, aggE, eW + l * EFD * EMB, eb + l * EMB);
        k_mlp<<<mlpBlocks, 256, 0, stream>>>(agg, agg, pw1 + l * EMB * HID, b1 + l * HID,
                                             pw2 + l * HID * EMB, b2 + l * EMB,
                                             stats + l * 2 * EMB);
        if (l < NLAYER - 1) {
            k_bn<<<(N_NODES * EMB + 255) / 256, 256, 0, stream>>>(
                agg, h, stats + l * 2 * EMB, gam + l * EMB, bet + l * EMB);
        } else {
            k_bnout<<<(NGRAPH * EMB + 255) / 256, 256, 0, stream>>>(
                agg, last, stats + l * 2 * EMB, gam + l * EMB, bet + l * EMB, out);
        }
    }
}